// Round 12
// baseline (346.340 us; speedup 1.0000x reference)
//
#include <hip/hip_runtime.h>

typedef int i32x4 __attribute__((ext_vector_type(4)));

// async 16B global->LDS (wave-uniform LDS base; HW scatters lane*16)
__device__ __forceinline__ void gl_lds16(const signed char* g, signed char* l) {
    __builtin_amdgcn_global_load_lds(
        (const __attribute__((address_space(1))) void*)g,
        (__attribute__((address_space(3))) void*)l, 16, 0, 0);
}

// LDS byte address (32-bit) of a __shared__ pointer — precomputed once, kept in VGPR.
__device__ __forceinline__ unsigned lds_addr(const signed char* p) {
    return (unsigned)(uintptr_t)(const __attribute__((address_space(3))) signed char*)p;
}

// inline-asm LDS read from a precomputed address (rule #18: consume only after
// asm lgkmcnt + sched_barrier).
__device__ __forceinline__ i32x4 lds_read_b128a(unsigned a) {
    i32x4 r;
    asm volatile("ds_read_b128 %0, %1" : "=v"(r) : "v"(a));
    return r;
}

#define XQ_SCALE 2048.0f
#define XQ_DELTA (1.0f / 2048.0f)

// ---------------- dispatch 1: EVERYTHING pre-conv, one kernel ----------------
// R11 post-mortem: non-conv rump ~102µs vs ~30µs of kernel-byte work -> dispatch
// overhead/serialization hypothesis. This kernel merges absmax+weight-quant+bias
// (old prep_w) INTO the pre kernel via device-scope self-synchronization:
//   - each w-quant block scans ITS slice -> atomicMax(global bits) -> release-add ctr
//     -> acquire-spin until its 512-block cohort done -> quantize (re-read, L2-hot).
//     fp-max is order-invariant -> bit-identical scale vs old two-stage reduction.
//   - deadlock-free: launch_bounds(256,8) forces <=64 VGPR -> 8 blocks/CU -> 2048
//     resident slots >> 1025 max spinners; non-spinning blocks retire, so all cohort
//     members eventually schedule. Spin throttled with s_sleep.
//   - sync area (16B at ws+0: ctr1,ctr2,max1bits,max2bits) zeroed per iteration by a
//     capture-safe hipMemsetAsync.
// Block map: [0,512) w1-quant | [512,1024) w2-quant | 1024 bias+wmax |
//            [1025,1489) x halo | [1489,1969) act halo | [1969,5169) x transform.
__global__ __launch_bounds__(256, 8) void mega_pre_kernel(
    const float* __restrict__ x,
    const float* __restrict__ w1, const float* __restrict__ w2,
    const float* __restrict__ b1, const float* __restrict__ b2,
    const float* __restrict__ in_scale, const float* __restrict__ act1_scale,
    unsigned* __restrict__ syn,          // [0]=ctr1 [1]=ctr2 [2]=max1 [3]=max2
    float* __restrict__ wmax,
    float* __restrict__ bq1, float* __restrict__ bq2,
    signed char* __restrict__ wq1, signed char* __restrict__ wq2,
    signed char* __restrict__ xhi, signed char* __restrict__ xlo,
    signed char* __restrict__ act)
{
    __shared__ __align__(16) signed char sw[4608];
    __shared__ float sred[8];
    const int blk = blockIdx.x;
    const int tid = threadIdx.x;
    const uint4 z = {0, 0, 0, 0};

    if (blk < 1024) {                      // ---- weight absmax + quant (self-synced)
        const bool second = blk >= 512;
        const int n = second ? (blk - 512) : blk;
        const int NF = second ? 1152 : 576;            // float4 per weight row-block
        const float4* src = (const float4*)((second ? w2 : w1) + n * (NF * 4));

        // pass 1: local absmax over this block's slice
        float m = 0.0f;
        for (int f = tid; f < NF; f += 256) {
            const float4 v = src[f];
            m = fmaxf(m, fmaxf(fmaxf(fabsf(v.x), fabsf(v.y)), fmaxf(fabsf(v.z), fabsf(v.w))));
        }
#pragma unroll
        for (int off = 32; off > 0; off >>= 1)
            m = fmaxf(m, __shfl_down(m, off));
        if ((tid & 63) == 0) sred[tid >> 6] = m;
        __syncthreads();
        if (tid == 0) {
            m = fmaxf(fmaxf(sred[0], sred[1]), fmaxf(sred[2], sred[3]));
            const int ci = second ? 1 : 0;
            atomicMax(&syn[2 + ci], __float_as_uint(m));           // bits monotonic (m>=0)
            __hip_atomic_fetch_add(&syn[ci], 1u, __ATOMIC_RELEASE, __HIP_MEMORY_SCOPE_AGENT);
            while (__hip_atomic_load(&syn[ci], __ATOMIC_ACQUIRE, __HIP_MEMORY_SCOPE_AGENT) < 512u)
                __builtin_amdgcn_s_sleep(8);
            sred[4] = __uint_as_float(
                __hip_atomic_load(&syn[2 + ci], __ATOMIC_ACQUIRE, __HIP_MEMORY_SCOPE_AGENT));
        }
        __syncthreads();
        const float inv_s = 127.0f / sred[4];

        // pass 2: quant + LDS transpose (identical numerics to prior prep_w)
        if (!second) {
#pragma unroll
            for (int rd = 0; rd < 3; ++rd) {
                const int f = rd * 256 + tid;          // float4 index < 576
                if (f < 576) {
                    const float4 v = src[f];
                    float q0 = fminf(fmaxf(rintf(v.x * inv_s), -127.0f), 127.0f);
                    float q1 = fminf(fmaxf(rintf(v.y * inv_s), -127.0f), 127.0f);
                    float q2 = fminf(fmaxf(rintf(v.z * inv_s), -127.0f), 127.0f);
                    float q3 = fminf(fmaxf(rintf(v.w * inv_s), -127.0f), 127.0f);
                    const int i0 = f * 4;
                    int cin, r;
                    cin = i0 / 9;     r = i0 - cin * 9;     sw[r * 256 + cin] = (signed char)(int)q0;
                    cin = (i0+1) / 9; r = (i0+1) - cin * 9; sw[r * 256 + cin] = (signed char)(int)q1;
                    cin = (i0+2) / 9; r = (i0+2) - cin * 9; sw[r * 256 + cin] = (signed char)(int)q2;
                    cin = (i0+3) / 9; r = (i0+3) - cin * 9; sw[r * 256 + cin] = (signed char)(int)q3;
                }
            }
            __syncthreads();
            if (tid < 144) *(uint4*)&wq1[n * 2304 + tid * 16] = *(const uint4*)&sw[tid * 16];
        } else {
#pragma unroll
            for (int rd = 0; rd < 5; ++rd) {
                const int f = rd * 256 + tid;          // float4 index < 1152
                if (f < 1152) {
                    const float4 v = src[f];
                    float q0 = fminf(fmaxf(rintf(v.x * inv_s), -127.0f), 127.0f);
                    float q1 = fminf(fmaxf(rintf(v.y * inv_s), -127.0f), 127.0f);
                    float q2 = fminf(fmaxf(rintf(v.z * inv_s), -127.0f), 127.0f);
                    float q3 = fminf(fmaxf(rintf(v.w * inv_s), -127.0f), 127.0f);
                    const int i0 = f * 4;
                    int cin, r;
                    cin = i0 / 9;     r = i0 - cin * 9;     sw[r * 512 + cin] = (signed char)(int)q0;
                    cin = (i0+1) / 9; r = (i0+1) - cin * 9; sw[r * 512 + cin] = (signed char)(int)q1;
                    cin = (i0+2) / 9; r = (i0+2) - cin * 9; sw[r * 512 + cin] = (signed char)(int)q2;
                    cin = (i0+3) / 9; r = (i0+3) - cin * 9; sw[r * 512 + cin] = (signed char)(int)q3;
                }
            }
            __syncthreads();
            for (int o = tid; o < 288; o += 256)
                *(uint4*)&wq2[n * 4608 + o * 16] = *(const uint4*)&sw[o * 16];
        }
    } else if (blk == 1024) {              // ---- bias quant + wmax (waits on both)
        if (tid == 0) {
            while (__hip_atomic_load(&syn[0], __ATOMIC_ACQUIRE, __HIP_MEMORY_SCOPE_AGENT) < 512u ||
                   __hip_atomic_load(&syn[1], __ATOMIC_ACQUIRE, __HIP_MEMORY_SCOPE_AGENT) < 512u)
                __builtin_amdgcn_s_sleep(8);
            sred[4] = __uint_as_float(
                __hip_atomic_load(&syn[2], __ATOMIC_ACQUIRE, __HIP_MEMORY_SCOPE_AGENT));
            sred[5] = __uint_as_float(
                __hip_atomic_load(&syn[3], __ATOMIC_ACQUIRE, __HIP_MEMORY_SCOPE_AGENT));
            wmax[0] = sred[4];
            wmax[1] = sred[5];
        }
        __syncthreads();
        const float m1 = sred[4];
        const float m2 = sred[5];
        for (int idx = tid; idx < 1024; idx += 256) {
            if (idx < 512) {
                const float s = (*in_scale) * (m1 * (1.0f / 127.0f));
                float q = rintf(b1[idx] / s);
                q = fminf(fmaxf(q, -2147483648.0f), 2147483648.0f);
                bq1[idx] = q * s;
            } else {
                const int j = idx - 512;
                const float s = (*act1_scale) * (m2 * (1.0f / 127.0f));
                float q = rintf(b2[j] / s);
                q = fminf(fmaxf(q, -2147483648.0f), 2147483648.0f);
                bq2[j] = q * s;
            }
        }
    } else if (blk < 1489) {               // ---- x halo (464 blocks)
        const int thr = (blk - 1025) * 256 + tid;   // < 64*116*16 = 118784
        const int b = thr / (116 * 16);
        const int rr = thr - b * (116 * 16);
        const int p = rr >> 4;
        const int ch = rr & 15;
        int h, w;
        if (p < 30)      { h = 0;          w = p; }
        else if (p < 60) { h = 29;         w = p - 30; }
        else if (p < 88) { h = p - 60 + 1; w = 0; }
        else             { h = p - 88 + 1; w = 29; }
        const int off = (b * 900 + h * 30 + w) * 256 + ch * 16;
        *(uint4*)(xhi + off) = z;
        *(uint4*)(xlo + off) = z;
    } else if (blk < 1969) {               // ---- act halo (480 blocks)
        const int thr = (blk - 1489) * 256 + tid;   // < 64*60*32 = 122880
        const int b = thr / (60 * 32);
        const int rr = thr - b * (60 * 32);
        const int p = rr >> 5;
        const int ch = rr & 31;
        int h, w;
        if (p < 16)      { h = 0;          w = p; }
        else if (p < 32) { h = 15;         w = p - 16; }
        else if (p < 46) { h = p - 32 + 1; w = 0; }
        else             { h = p - 46 + 1; w = 15; }
        const int off = (b * 256 + h * 16 + w) * 512 + ch * 16;
        *(uint4*)(act + off) = z;
    } else {                               // ---- x transform (3200 blocks, direct)
        const int xb = blk - 1969;         // < 3200
        const int hwb = xb % 25;
        const int rest = xb / 25;
        const int cb = rest & 1;
        const int b = rest >> 1;
        const int c0 = cb * 128 + (tid >> 5) * 16;   // this thread's 16-channel group
        const int hw = hwb * 32 + (tid & 31);
        if (hw < 784) {
            const float* xp = x + (b * 256 + c0) * 784 + hw;
            union { signed char c[16]; uint4 u; } ph, pl;
#pragma unroll
            for (int j = 0; j < 16; ++j) {
                const float v = xp[j * 784];
                int q = (int)rintf(v * XQ_SCALE);
                q = max(-16383, min(16383, q));
                ph.c[j] = (signed char)(q >> 7);     // [-128,127]
                pl.c[j] = (signed char)(q & 127);    // [0,127]; q == 128*qh + ql
            }
            const int r = hw / 28;
            const int o = (b * 900 + (r + 1) * 30 + (hw - r * 28) + 1) * 256 + c0;
            *(uint4*)&xhi[o] = ph.u;
            *(uint4*)&xlo[o] = pl.u;
        }
    }
}

// ---------------- implicit-GEMM conv, i8 MFMA, 64m x 128n block, 4 waves ---------------
// R11 VERBATIM (best measured): R7 counted-vmcnt pipeline + T1 XCD-aware bijective
// chunked block->tile swizzle (conv1 FETCH 87.5->~44MB, conv2 35->17.5MB).
template<int CIN, int STRIDE, int HP, int HOUT, bool SPLIT, bool FINAL>
__global__ __launch_bounds__(256, SPLIT ? 2 : 3) void conv_gemm_kernel(
    const signed char* __restrict__ Ahi,
    const signed char* __restrict__ Alo,
    const signed char* __restrict__ Wt,
    const float* __restrict__ bias,
    const float* __restrict__ wmax,
    const float* __restrict__ s_pre,
    const float* __restrict__ s_act,
    signed char* __restrict__ act_out,  // !FINAL: padded NHWC i8 codes [64][16][16][512]
    float* __restrict__ out_final)      // FINAL: NCHW fp32
{
    constexpr int K = 9 * CIN;
    constexpr int HW = HOUT * HOUT;
    constexpr int NIT = K / 128;                  // windows: 18 (conv1) / 36 (conv2), even
    constexpr int NC = SPLIT ? 8 : 6;             // staging chunks per wave per window
    constexpr int BUFSZ = SPLIT ? 32768 : 24576;  // one buffer set
    constexpr int NB = SPLIT ? 4 : 2;             // n-fragments per wave

    __shared__ __align__(16) signed char smem[2 * BUFSZ];

    const int tid = threadIdx.x;
    const int lane = tid & 63;
    const int wv = tid >> 6;            // 0..3
    const int pair = wv >> 1;
    const int nh = wv & 1;              // n-half within pair (SPLIT epilogue)
    const int quad = lane >> 4;
    const int l16 = lane & 15;

    // ---- XCD-aware bijective chunked swizzle (784 blocks, 784 % 8 == 0) ----
    const int lin = blockIdx.x + (int)gridDim.x * blockIdx.y;    // 0..783
    const int swz = (lin & 7) * 98 + (lin >> 3);                 // chunk of 98 per XCD
    const int n0 = (swz & 3) * 128;
    const int m0 = (swz >> 2) * 64;

    // staging: chunk = 1KB = 8 rows x 128B; lane -> (row lane>>3, phys slot lane&7)
    const int lrow = lane >> 3;
    const int koff = ((lane & 7) ^ lrow) * 16;   // swizzled logical k-offset

    const signed char* srcb[NC];
    int dsto[NC];
    bool isA[NC];
    if constexpr (SPLIT) {
#pragma unroll
        for (int i = 0; i < NC; ++i) {
            const int g = wv * 8 + i;
            const int type = g >> 3;        // 0=A-hi (wave0), 1=A-lo (wave1), 2,3=B
            if (type >= 2) {
                const int c = g - 16;
                srcb[i] = Wt + (n0 + c * 8 + lrow) * K + koff;
                dsto[i] = 16384 + c * 1024;
                isA[i] = false;
            } else {
                const int c = g & 7;
                const int m = m0 + c * 8 + lrow;
                const int b = m / HW;
                const int rem = m - b * HW;
                const int oh = rem / HOUT;
                const int ow = rem - oh * HOUT;
                const int off = ((b * HP + oh * STRIDE) * HP + ow * STRIDE) * CIN + koff;
                srcb[i] = (type == 0 ? Ahi : Alo) + off;
                dsto[i] = type * 8192 + c * 1024;
                isA[i] = true;
            }
        }
    } else {
#pragma unroll
        for (int i = 0; i < NC; ++i) {
            const int g = wv * 6 + i;       // 24 chunks total: 8 A + 16 B
            if (g < 8) {
                const int c = g;
                const int m = m0 + c * 8 + lrow;
                const int b = m / HW;
                const int rem = m - b * HW;
                const int oh = rem / HOUT;
                const int ow = rem - oh * HOUT;
                const int off = ((b * HP + oh * STRIDE) * HP + ow * STRIDE) * CIN + koff;
                srcb[i] = Ahi + off;
                dsto[i] = c * 1024;
                isA[i] = true;
            } else {
                const int c = g - 8;
                srcb[i] = Wt + (n0 + c * 8 + lrow) * K + koff;
                dsto[i] = 8192 + c * 1024;
                isA[i] = false;
            }
        }
    }

    const int aoff0 = SPLIT ? (pair * 8192) : 0;     // relative to buffer base
    const int boff0 = SPLIT ? 16384 : 8192;
    const int nfix  = SPLIT ? (nh * 64) : (wv * 32); // wave's n-offset within 128

    // ---- precomputed LDS read addresses: [buf][ks][frag] ----
    unsigned aad[2][2][4];
    unsigned bad[2][2][NB];
#pragma unroll
    for (int bi = 0; bi < 2; ++bi)
#pragma unroll
        for (int ks = 0; ks < 2; ++ks) {
#pragma unroll
            for (int mi = 0; mi < 4; ++mi) {
                const int row = mi * 16 + l16;
                const int sl = ((ks * 4 + quad) ^ (row & 7)) * 16;
                aad[bi][ks][mi] = lds_addr(&smem[bi * BUFSZ + aoff0 + row * 128 + sl]);
            }
#pragma unroll
            for (int ni = 0; ni < NB; ++ni) {
                const int row = nfix + ni * 16 + l16;
                const int sl = ((ks * 4 + quad) ^ (row & 7)) * 16;
                bad[bi][ks][ni] = lds_addr(&smem[bi * BUFSZ + boff0 + row * 128 + sl]);
            }
        }

    i32x4 acc[4][NB];
#pragma unroll
    for (int mi = 0; mi < 4; ++mi)
#pragma unroll
        for (int ni = 0; ni < NB; ++ni)
            acc[mi][ni] = i32x4{0, 0, 0, 0};

    // issue this wave's NC chunks for window `it` into buffer at byte offset `bo`
    auto STAGE = [&](int bo, int it) {
        const int k0 = it * 128;
        const int r9 = k0 / CIN;            // wave-uniform
        const int kh = r9 / 3;
        const int kw = r9 - kh * 3;
        const int ashift = (kh * HP + kw) * CIN + (k0 & (CIN - 1));
#pragma unroll
        for (int i = 0; i < NC; ++i)
            gl_lds16(srcb[i] + (isA[i] ? ashift : k0), &smem[bo + dsto[i]]);
    };

    i32x4 af[2][4], bf[2][NB];

    // pure ds_read issue from precomputed addresses (ks0 first -> counted lgkm gates ks0)
    auto LOADFRAGS = [&](int bi) {
#pragma unroll
        for (int ks = 0; ks < 2; ++ks) {
#pragma unroll
            for (int mi = 0; mi < 4; ++mi)
                af[ks][mi] = lds_read_b128a(aad[bi][ks][mi]);
#pragma unroll
            for (int ni = 0; ni < NB; ++ni)
                bf[ks][ni] = lds_read_b128a(bad[bi][ks][ni]);
        }
    };

    auto MFMAS_KS = [&](int ks) {
        __builtin_amdgcn_s_setprio(1);
#pragma unroll
        for (int mi = 0; mi < 4; ++mi)
#pragma unroll
            for (int ni = 0; ni < NB; ++ni)
                acc[mi][ni] = __builtin_amdgcn_mfma_i32_16x16x64_i8(af[ks][mi], bf[ks][ni], acc[mi][ni], 0, 0, 0);
        __builtin_amdgcn_s_setprio(0);
    };

    auto WAIT_NC = [&]() {   // wait until only the newest NC loads remain in flight
        if constexpr (SPLIT) asm volatile("s_waitcnt vmcnt(8)" ::: "memory");
        else                 asm volatile("s_waitcnt vmcnt(6)" ::: "memory");
    };
    auto LGKM_HALF = [&]() { // ks0 frag reads landed; ks1's still in flight
        if constexpr (SPLIT) asm volatile("s_waitcnt lgkmcnt(8)" ::: "memory");
        else                 asm volatile("s_waitcnt lgkmcnt(6)" ::: "memory");
    };

    // ---- prologue: fill both buffers (2*NC loads in flight) ----
    STAGE(0, 0);
    STAGE(BUFSZ, 1);

    // ---- steady state: windows 0..NIT-3 ----
    for (int it = 0; it < NIT - 2; it += 2) {
        // window `it` in buf0
        WAIT_NC();
        __builtin_amdgcn_s_barrier();
        __builtin_amdgcn_sched_barrier(0);
        LOADFRAGS(0);
        LGKM_HALF();
        __builtin_amdgcn_sched_barrier(0);
        MFMAS_KS(0);                            // overlaps ks1 ds_reads
        asm volatile("s_waitcnt lgkmcnt(0)" ::: "memory");
        __builtin_amdgcn_sched_barrier(0);
        __builtin_amdgcn_s_barrier();           // all waves done reading buf0
        __builtin_amdgcn_sched_barrier(0);
        STAGE(0, it + 2);
        MFMAS_KS(1);                            // overlaps staging issue

        // window `it+1` in buf1
        WAIT_NC();
        __builtin_amdgcn_s_barrier();
        __builtin_amdgcn_sched_barrier(0);
        LOADFRAGS(1);
        LGKM_HALF();
        __builtin_amdgcn_sched_barrier(0);
        MFMAS_KS(0);
        asm volatile("s_waitcnt lgkmcnt(0)" ::: "memory");
        __builtin_amdgcn_sched_barrier(0);
        __builtin_amdgcn_s_barrier();           // all waves done reading buf1
        __builtin_amdgcn_sched_barrier(0);
        if (it + 3 < NIT) STAGE(BUFSZ, it + 3);
        MFMAS_KS(1);
    }

    // ---- peel window NIT-2 (buf0): nothing stages into buf0 afterwards ----
    WAIT_NC();
    __builtin_amdgcn_s_barrier();
    __builtin_amdgcn_sched_barrier(0);
    LOADFRAGS(0);
    LGKM_HALF();
    __builtin_amdgcn_sched_barrier(0);
    MFMAS_KS(0);
    asm volatile("s_waitcnt lgkmcnt(0)" ::: "memory");
    __builtin_amdgcn_sched_barrier(0);
    MFMAS_KS(1);

    // ---- peel window NIT-1 (buf1) ----
    asm volatile("s_waitcnt vmcnt(0)" ::: "memory");
    __builtin_amdgcn_s_barrier();
    __builtin_amdgcn_sched_barrier(0);
    LOADFRAGS(1);
    LGKM_HALF();
    __builtin_amdgcn_sched_barrier(0);
    MFMAS_KS(0);
    asm volatile("s_waitcnt lgkmcnt(0)" ::: "memory");
    __builtin_amdgcn_sched_barrier(0);
    MFMAS_KS(1);

    if constexpr (SPLIT) {
        // ---- pair combine through LDS (reuse staging space) ----
        __syncthreads();
        if (pair == 1) {
#pragma unroll
            for (int mi = 0; mi < 4; ++mi)
#pragma unroll
                for (int ni = 0; ni < 4; ++ni)
                    *(i32x4*)&smem[nh * 16384 + (mi * 4 + ni) * 1024 + lane * 16] = acc[mi][ni];
        }
        __syncthreads();
        if (pair == 1) return;
#pragma unroll
        for (int mi = 0; mi < 4; ++mi)
#pragma unroll
            for (int ni = 0; ni < 4; ++ni) {
                const i32x4 other = *(const i32x4*)&smem[nh * 16384 + (mi * 4 + ni) * 1024 + lane * 16];
                acc[mi][ni] = acc[mi][ni] * 128 + other;   // 128*hi + lo
            }
    }

    // ---- epilogue: dequant, add quantized bias, act fake-quant ----
    float alpha = (*wmax) * (1.0f / 127.0f);
    if (FINAL) alpha *= *s_pre;      // conv2: acc * (s_a1 * s_w2)
    if (SPLIT) alpha *= XQ_DELTA;    // conv1: fixed-point dequant
    const float sact = *s_act;

    float bv[NB];
#pragma unroll
    for (int ni = 0; ni < NB; ++ni)
        bv[ni] = bias[n0 + nfix + ni * 16 + l16];

#pragma unroll
    for (int mi = 0; mi < 4; ++mi) {
#pragma unroll
        for (int i = 0; i < 4; ++i) {
            const int m = m0 + mi * 16 + quad * 4 + i;   // D row = quad*4+i
            const int b = m / HW;
            const int rem = m - b * HW;
            const int oh = rem / HOUT;
            const int ow = rem - oh * HOUT;
#pragma unroll
            for (int ni = 0; ni < NB; ++ni) {
                const int col = n0 + nfix + ni * 16 + l16;   // D col = l16
                const float v = (float)acc[mi][ni][i] * alpha + bv[ni];
                float q = rintf(v / sact);
                q = fminf(fmaxf(q, -128.0f), 127.0f);
                if (FINAL) {
                    out_final[(b * 512 + col) * HW + oh * HOUT + ow] = q * sact;
                } else {
                    act_out[(b * 256 + (oh + 1) * 16 + (ow + 1)) * 512 + col] = (signed char)(int)q;
                }
            }
        }
    }
}

// ---------------- launch ----------------
extern "C" void kernel_launch(void* const* d_in, const int* in_sizes, int n_in,
                              void* d_out, int out_size, void* d_ws, size_t ws_size,
                              hipStream_t stream) {
    const float* x  = (const float*)d_in[0];   // 64x256x28x28
    const float* w1 = (const float*)d_in[1];   // 512x256x3x3
    const float* b1 = (const float*)d_in[2];   // 512
    const float* w2 = (const float*)d_in[3];   // 512x512x3x3
    const float* b2 = (const float*)d_in[4];   // 512
    const float* in_scale   = (const float*)d_in[5];
    const float* act1_scale = (const float*)d_in[6];
    const float* act2_scale = (const float*)d_in[7];
    float* out = (float*)d_out;                // 64x512x14x14 NCHW fp32

    char* ws = (char*)d_ws;
    unsigned* syn = (unsigned*)(ws + 0);                // 16B: ctr1, ctr2, max1, max2
    float* wmax = (float*)(ws + 2048);                  // 2 floats
    float* bq1 = (float*)(ws + 2176);                   // 512 f
    float* bq2 = (float*)(ws + 4224);                   // 512 f
    signed char* wq1 = (signed char*)(ws + 8192);       // 512*2304 = 1,179,648
    signed char* wq2 = (signed char*)(ws + 1187840);    // 512*4608 = 2,359,296
    signed char* xhi = (signed char*)(ws + 3547136);    // 64*900*256 = 14,745,600
    signed char* xlo = (signed char*)(ws + 18292736);   // 14,745,600
    signed char* act = (signed char*)(ws + 33038336);   // 64*256*512 = 8,388,608 -> ends 41,426,944

    // dispatch 0: zero the 16B sync area (capture-safe async memset)
    hipMemsetAsync(ws, 0, 16, stream);

    // dispatch 1: ALL pre-conv work in one kernel (absmax+quant self-synced via
    // device-scope atomics; halos + x transform ride alongside and hide the spin)
    mega_pre_kernel<<<5169, 256, 0, stream>>>(x, w1, w2, b1, b2, in_scale, act1_scale,
                                              syn, wmax, bq1, bq2, wq1, wq2,
                                              xhi, xlo, act);

    // conv1: 256->512, s2, padded 30x30 in, hi/lo limb pairs, padded act codes out
    conv_gemm_kernel<256, 2, 30, 14, true, false><<<dim3(4, 196), 256, 0, stream>>>(
        xhi, xlo, wq1, bq1, wmax, act1_scale, act1_scale, act, nullptr);

    // conv2: 512->512, s1, padded 16x16 in (exact i8 codes), full-K per wave, fp32 NCHW out
    conv_gemm_kernel<512, 1, 16, 14, false, true><<<dim3(4, 196), 256, 0, stream>>>(
        act, nullptr, wq2, bq2, wmax + 1, act1_scale, act2_scale, nullptr, out);
}

// Round 13
// 224.005 us; speedup vs baseline: 1.5461x; 1.5461x over previous
//
#include <hip/hip_runtime.h>

typedef int i32x4 __attribute__((ext_vector_type(4)));

// async 16B global->LDS (wave-uniform LDS base; HW scatters lane*16)
__device__ __forceinline__ void gl_lds16(const signed char* g, signed char* l) {
    __builtin_amdgcn_global_load_lds(
        (const __attribute__((address_space(1))) void*)g,
        (__attribute__((address_space(3))) void*)l, 16, 0, 0);
}

// LDS byte address (32-bit) of a __shared__ pointer — precomputed once, kept in VGPR.
__device__ __forceinline__ unsigned lds_addr(const signed char* p) {
    return (unsigned)(uintptr_t)(const __attribute__((address_space(3))) signed char*)p;
}

// inline-asm LDS read from a precomputed address (rule #18: consume only after
// asm lgkmcnt + sched_barrier).
__device__ __forceinline__ i32x4 lds_read_b128a(unsigned a) {
    i32x4 r;
    asm volatile("ds_read_b128 %0, %1" : "=v"(r) : "v"(a));
    return r;
}

#define XQ_SCALE 2048.0f
#define XQ_DELTA (1.0f / 2048.0f)

// reduce 256 partials to a block-wide max (all 256 threads participate)
__device__ __forceinline__ float block_max256(const float* __restrict__ part, int base,
                                              float* __restrict__ sred) {
    float m = part[base + (threadIdx.x & 255)];
#pragma unroll
    for (int off = 32; off > 0; off >>= 1)
        m = fmaxf(m, __shfl_down(m, off));
    __syncthreads();
    if ((threadIdx.x & 63) == 0) sred[threadIdx.x >> 6] = m;
    __syncthreads();
    return fmaxf(fmaxf(sred[0], sred[1]), fmaxf(sred[2], sred[3]));
}

// ---------------- dispatch 1: absmax partials + halos + x transform ----------------
// Transform = R8's direct scalar form (best measured rump): no LDS, lane map
// (hw = tid&31, c-group = tid>>5) gives coalesced reads per j; one 16B write per array.
// NOTE (R12 lesson): merging prep into this kernel via device-scope spin-sync costs
// ~100µs in cross-XCD coherence spin — kernel-boundary sync is strictly cheaper.
__global__ __launch_bounds__(256) void fused_pre_kernel(
    const float* __restrict__ x,
    const float* __restrict__ w1, const float* __restrict__ w2,
    float* __restrict__ part,
    signed char* __restrict__ xhi, signed char* __restrict__ xlo,
    signed char* __restrict__ act) {
    __shared__ float sred[4];
    const int blk = blockIdx.x;
    const int tid = threadIdx.x;
    const uint4 z = {0, 0, 0, 0};

    if (blk < 512) {                       // ---- absmax partials
        const bool second = blk >= 256;
        const float* w = second ? w2 : w1;
        const int n4 = second ? 589824 : 294912;   // elements/4
        float m = 0.0f;
        for (int i = (blk & 255) * 256 + tid; i < n4; i += 65536) {
            float4 v = ((const float4*)w)[i];
            m = fmaxf(m, fmaxf(fmaxf(fabsf(v.x), fabsf(v.y)), fmaxf(fabsf(v.z), fabsf(v.w))));
        }
#pragma unroll
        for (int off = 32; off > 0; off >>= 1)
            m = fmaxf(m, __shfl_down(m, off));
        if ((tid & 63) == 0) sred[tid >> 6] = m;
        __syncthreads();
        if (tid == 0)
            part[blk] = fmaxf(fmaxf(sred[0], sred[1]), fmaxf(sred[2], sred[3]));
    } else if (blk < 976) {                // ---- x halo
        const int thr = (blk - 512) * 256 + tid;   // < 64*116*16 = 118784
        const int b = thr / (116 * 16);
        const int rr = thr - b * (116 * 16);
        const int p = rr >> 4;
        const int ch = rr & 15;
        int h, w;
        if (p < 30)      { h = 0;          w = p; }
        else if (p < 60) { h = 29;         w = p - 30; }
        else if (p < 88) { h = p - 60 + 1; w = 0; }
        else             { h = p - 88 + 1; w = 29; }
        const int off = (b * 900 + h * 30 + w) * 256 + ch * 16;
        *(uint4*)(xhi + off) = z;
        *(uint4*)(xlo + off) = z;
    } else if (blk < 1456) {               // ---- act halo
        const int thr = (blk - 976) * 256 + tid;   // < 64*60*32 = 122880
        const int b = thr / (60 * 32);
        const int rr = thr - b * (60 * 32);
        const int p = rr >> 5;
        const int ch = rr & 31;
        int h, w;
        if (p < 16)      { h = 0;          w = p; }
        else if (p < 32) { h = 15;         w = p - 16; }
        else if (p < 46) { h = p - 32 + 1; w = 0; }
        else             { h = p - 46 + 1; w = 15; }
        const int off = (b * 256 + h * 16 + w) * 512 + ch * 16;
        *(uint4*)(act + off) = z;
    } else {                               // ---- x transform (direct, no LDS)
        const int xb = blk - 1456;         // < 3200
        const int hwb = xb % 25;
        const int rest = xb / 25;
        const int cb = rest & 1;
        const int b = rest >> 1;
        const int c0 = cb * 128 + (tid >> 5) * 16;   // this thread's 16-channel group
        const int hw = hwb * 32 + (tid & 31);
        if (hw < 784) {
            const float* xp = x + (b * 256 + c0) * 784 + hw;
            union { signed char c[16]; uint4 u; } ph, pl;
#pragma unroll
            for (int j = 0; j < 16; ++j) {
                const float v = xp[j * 784];
                int q = (int)rintf(v * XQ_SCALE);
                q = max(-16383, min(16383, q));
                ph.c[j] = (signed char)(q >> 7);     // [-128,127]
                pl.c[j] = (signed char)(q & 127);    // [0,127]; q == 128*qh + ql
            }
            const int r = hw / 28;
            const int o = (b * 900 + (r + 1) * 30 + (hw - r * 28) + 1) * 256 + c0;
            *(uint4*)&xhi[o] = ph.u;
            *(uint4*)&xlo[o] = pl.u;
        }
    }
}

// ---------------- dispatch 2: weight quant+transpose, bias quant, wmax ----------------
// (R6: float4 weight reads; kept verbatim.)
__global__ __launch_bounds__(256) void prep_w_kernel(
    const float* __restrict__ w1, const float* __restrict__ w2,
    const float* __restrict__ b1, const float* __restrict__ b2,
    const float* __restrict__ part,
    const float* __restrict__ in_scale, const float* __restrict__ act1_scale,
    signed char* __restrict__ wq1, signed char* __restrict__ wq2,
    float* __restrict__ bq1, float* __restrict__ bq2,
    float* __restrict__ wmax) {
    __shared__ __align__(16) signed char sw[4608];
    __shared__ float sred[4];
    const int blk = blockIdx.x;
    const int tid = threadIdx.x;

    if (blk < 512) {                       // ---- w1 quant+transpose
        const float inv_s = 127.0f / block_max256(part, 0, sred);
        const int n = blk;
        const float4* src = (const float4*)(w1 + n * 2304);
#pragma unroll
        for (int rd = 0; rd < 3; ++rd) {
            const int f = rd * 256 + tid;              // float4 index < 576
            if (f < 576) {
                const float4 v = src[f];
                float q0 = fminf(fmaxf(rintf(v.x * inv_s), -127.0f), 127.0f);
                float q1 = fminf(fmaxf(rintf(v.y * inv_s), -127.0f), 127.0f);
                float q2 = fminf(fmaxf(rintf(v.z * inv_s), -127.0f), 127.0f);
                float q3 = fminf(fmaxf(rintf(v.w * inv_s), -127.0f), 127.0f);
                const int i0 = f * 4;
                int cin, r;
                cin = i0 / 9;       r = i0 - cin * 9;       sw[r * 256 + cin] = (signed char)(int)q0;
                cin = (i0+1) / 9;   r = (i0+1) - cin * 9;   sw[r * 256 + cin] = (signed char)(int)q1;
                cin = (i0+2) / 9;   r = (i0+2) - cin * 9;   sw[r * 256 + cin] = (signed char)(int)q2;
                cin = (i0+3) / 9;   r = (i0+3) - cin * 9;   sw[r * 256 + cin] = (signed char)(int)q3;
            }
        }
        __syncthreads();
        if (tid < 144) *(uint4*)&wq1[n * 2304 + tid * 16] = *(const uint4*)&sw[tid * 16];
    } else if (blk < 1024) {               // ---- w2 quant+transpose
        const float inv_s = 127.0f / block_max256(part, 256, sred);
        const int n = blk - 512;
        const float4* src = (const float4*)(w2 + n * 4608);
#pragma unroll
        for (int rd = 0; rd < 5; ++rd) {
            const int f = rd * 256 + tid;              // float4 index < 1152
            if (f < 1152) {
                const float4 v = src[f];
                float q0 = fminf(fmaxf(rintf(v.x * inv_s), -127.0f), 127.0f);
                float q1 = fminf(fmaxf(rintf(v.y * inv_s), -127.0f), 127.0f);
                float q2 = fminf(fmaxf(rintf(v.z * inv_s), -127.0f), 127.0f);
                float q3 = fminf(fmaxf(rintf(v.w * inv_s), -127.0f), 127.0f);
                const int i0 = f * 4;
                int cin, r;
                cin = i0 / 9;       r = i0 - cin * 9;       sw[r * 512 + cin] = (signed char)(int)q0;
                cin = (i0+1) / 9;   r = (i0+1) - cin * 9;   sw[r * 512 + cin] = (signed char)(int)q1;
                cin = (i0+2) / 9;   r = (i0+2) - cin * 9;   sw[r * 512 + cin] = (signed char)(int)q2;
                cin = (i0+3) / 9;   r = (i0+3) - cin * 9;   sw[r * 512 + cin] = (signed char)(int)q3;
            }
        }
        __syncthreads();
        for (int o = tid; o < 288; o += 256)
            *(uint4*)&wq2[n * 4608 + o * 16] = *(const uint4*)&sw[o * 16];
    } else {                               // ---- bias quant + wmax
        const float m1 = block_max256(part, 0, sred);
        const float m2 = block_max256(part, 256, sred);
        if (tid == 0) { wmax[0] = m1; wmax[1] = m2; }
        for (int idx = tid; idx < 1024; idx += 256) {
            if (idx < 512) {
                const float s = (*in_scale) * (m1 * (1.0f / 127.0f));
                float q = rintf(b1[idx] / s);
                q = fminf(fmaxf(q, -2147483648.0f), 2147483648.0f);
                bq1[idx] = q * s;
            } else {
                const int j = idx - 512;
                const float s = (*act1_scale) * (m2 * (1.0f / 127.0f));
                float q = rintf(b2[j] / s);
                q = fminf(fmaxf(q, -2147483648.0f), 2147483648.0f);
                bq2[j] = q * s;
            }
        }
    }
}

// ---------------- implicit-GEMM conv, i8 MFMA, 64m x 128n block, 4 waves ---------------
// R7 counted-vmcnt pipeline + T1 XCD-aware bijective chunked block->tile swizzle
// (conv1 FETCH 87.5->~44MB, conv2 35->17.5MB; -5µs total). Session-best conv structure.
template<int CIN, int STRIDE, int HP, int HOUT, bool SPLIT, bool FINAL>
__global__ __launch_bounds__(256, SPLIT ? 2 : 3) void conv_gemm_kernel(
    const signed char* __restrict__ Ahi,
    const signed char* __restrict__ Alo,
    const signed char* __restrict__ Wt,
    const float* __restrict__ bias,
    const float* __restrict__ wmax,
    const float* __restrict__ s_pre,
    const float* __restrict__ s_act,
    signed char* __restrict__ act_out,  // !FINAL: padded NHWC i8 codes [64][16][16][512]
    float* __restrict__ out_final)      // FINAL: NCHW fp32
{
    constexpr int K = 9 * CIN;
    constexpr int HW = HOUT * HOUT;
    constexpr int NIT = K / 128;                  // windows: 18 (conv1) / 36 (conv2), even
    constexpr int NC = SPLIT ? 8 : 6;             // staging chunks per wave per window
    constexpr int BUFSZ = SPLIT ? 32768 : 24576;  // one buffer set
    constexpr int NB = SPLIT ? 4 : 2;             // n-fragments per wave

    __shared__ __align__(16) signed char smem[2 * BUFSZ];

    const int tid = threadIdx.x;
    const int lane = tid & 63;
    const int wv = tid >> 6;            // 0..3
    const int pair = wv >> 1;
    const int nh = wv & 1;              // n-half within pair (SPLIT epilogue)
    const int quad = lane >> 4;
    const int l16 = lane & 15;

    // ---- XCD-aware bijective chunked swizzle (784 blocks, 784 % 8 == 0) ----
    const int lin = blockIdx.x + (int)gridDim.x * blockIdx.y;    // 0..783
    const int swz = (lin & 7) * 98 + (lin >> 3);                 // chunk of 98 per XCD
    const int n0 = (swz & 3) * 128;
    const int m0 = (swz >> 2) * 64;

    // staging: chunk = 1KB = 8 rows x 128B; lane -> (row lane>>3, phys slot lane&7)
    const int lrow = lane >> 3;
    const int koff = ((lane & 7) ^ lrow) * 16;   // swizzled logical k-offset

    const signed char* srcb[NC];
    int dsto[NC];
    bool isA[NC];
    if constexpr (SPLIT) {
#pragma unroll
        for (int i = 0; i < NC; ++i) {
            const int g = wv * 8 + i;
            const int type = g >> 3;        // 0=A-hi (wave0), 1=A-lo (wave1), 2,3=B
            if (type >= 2) {
                const int c = g - 16;
                srcb[i] = Wt + (n0 + c * 8 + lrow) * K + koff;
                dsto[i] = 16384 + c * 1024;
                isA[i] = false;
            } else {
                const int c = g & 7;
                const int m = m0 + c * 8 + lrow;
                const int b = m / HW;
                const int rem = m - b * HW;
                const int oh = rem / HOUT;
                const int ow = rem - oh * HOUT;
                const int off = ((b * HP + oh * STRIDE) * HP + ow * STRIDE) * CIN + koff;
                srcb[i] = (type == 0 ? Ahi : Alo) + off;
                dsto[i] = type * 8192 + c * 1024;
                isA[i] = true;
            }
        }
    } else {
#pragma unroll
        for (int i = 0; i < NC; ++i) {
            const int g = wv * 6 + i;       // 24 chunks total: 8 A + 16 B
            if (g < 8) {
                const int c = g;
                const int m = m0 + c * 8 + lrow;
                const int b = m / HW;
                const int rem = m - b * HW;
                const int oh = rem / HOUT;
                const int ow = rem - oh * HOUT;
                const int off = ((b * HP + oh * STRIDE) * HP + ow * STRIDE) * CIN + koff;
                srcb[i] = Ahi + off;
                dsto[i] = c * 1024;
                isA[i] = true;
            } else {
                const int c = g - 8;
                srcb[i] = Wt + (n0 + c * 8 + lrow) * K + koff;
                dsto[i] = 8192 + c * 1024;
                isA[i] = false;
            }
        }
    }

    const int aoff0 = SPLIT ? (pair * 8192) : 0;     // relative to buffer base
    const int boff0 = SPLIT ? 16384 : 8192;
    const int nfix  = SPLIT ? (nh * 64) : (wv * 32); // wave's n-offset within 128

    // ---- precomputed LDS read addresses: [buf][ks][frag] ----
    unsigned aad[2][2][4];
    unsigned bad[2][2][NB];
#pragma unroll
    for (int bi = 0; bi < 2; ++bi)
#pragma unroll
        for (int ks = 0; ks < 2; ++ks) {
#pragma unroll
            for (int mi = 0; mi < 4; ++mi) {
                const int row = mi * 16 + l16;
                const int sl = ((ks * 4 + quad) ^ (row & 7)) * 16;
                aad[bi][ks][mi] = lds_addr(&smem[bi * BUFSZ + aoff0 + row * 128 + sl]);
            }
#pragma unroll
            for (int ni = 0; ni < NB; ++ni) {
                const int row = nfix + ni * 16 + l16;
                const int sl = ((ks * 4 + quad) ^ (row & 7)) * 16;
                bad[bi][ks][ni] = lds_addr(&smem[bi * BUFSZ + boff0 + row * 128 + sl]);
            }
        }

    i32x4 acc[4][NB];
#pragma unroll
    for (int mi = 0; mi < 4; ++mi)
#pragma unroll
        for (int ni = 0; ni < NB; ++ni)
            acc[mi][ni] = i32x4{0, 0, 0, 0};

    // issue this wave's NC chunks for window `it` into buffer at byte offset `bo`
    auto STAGE = [&](int bo, int it) {
        const int k0 = it * 128;
        const int r9 = k0 / CIN;            // wave-uniform
        const int kh = r9 / 3;
        const int kw = r9 - kh * 3;
        const int ashift = (kh * HP + kw) * CIN + (k0 & (CIN - 1));
#pragma unroll
        for (int i = 0; i < NC; ++i)
            gl_lds16(srcb[i] + (isA[i] ? ashift : k0), &smem[bo + dsto[i]]);
    };

    i32x4 af[2][4], bf[2][NB];

    // pure ds_read issue from precomputed addresses (ks0 first -> counted lgkm gates ks0)
    auto LOADFRAGS = [&](int bi) {
#pragma unroll
        for (int ks = 0; ks < 2; ++ks) {
#pragma unroll
            for (int mi = 0; mi < 4; ++mi)
                af[ks][mi] = lds_read_b128a(aad[bi][ks][mi]);
#pragma unroll
            for (int ni = 0; ni < NB; ++ni)
                bf[ks][ni] = lds_read_b128a(bad[bi][ks][ni]);
        }
    };

    auto MFMAS_KS = [&](int ks) {
        __builtin_amdgcn_s_setprio(1);
#pragma unroll
        for (int mi = 0; mi < 4; ++mi)
#pragma unroll
            for (int ni = 0; ni < NB; ++ni)
                acc[mi][ni] = __builtin_amdgcn_mfma_i32_16x16x64_i8(af[ks][mi], bf[ks][ni], acc[mi][ni], 0, 0, 0);
        __builtin_amdgcn_s_setprio(0);
    };

    auto WAIT_NC = [&]() {   // wait until only the newest NC loads remain in flight
        if constexpr (SPLIT) asm volatile("s_waitcnt vmcnt(8)" ::: "memory");
        else                 asm volatile("s_waitcnt vmcnt(6)" ::: "memory");
    };
    auto LGKM_HALF = [&]() { // ks0 frag reads landed; ks1's still in flight
        if constexpr (SPLIT) asm volatile("s_waitcnt lgkmcnt(8)" ::: "memory");
        else                 asm volatile("s_waitcnt lgkmcnt(6)" ::: "memory");
    };

    // ---- prologue: fill both buffers (2*NC loads in flight) ----
    STAGE(0, 0);
    STAGE(BUFSZ, 1);

    // ---- steady state: windows 0..NIT-3 ----
    for (int it = 0; it < NIT - 2; it += 2) {
        // window `it` in buf0
        WAIT_NC();
        __builtin_amdgcn_s_barrier();
        __builtin_amdgcn_sched_barrier(0);
        LOADFRAGS(0);
        LGKM_HALF();
        __builtin_amdgcn_sched_barrier(0);
        MFMAS_KS(0);                            // overlaps ks1 ds_reads
        asm volatile("s_waitcnt lgkmcnt(0)" ::: "memory");
        __builtin_amdgcn_sched_barrier(0);
        __builtin_amdgcn_s_barrier();           // all waves done reading buf0
        __builtin_amdgcn_sched_barrier(0);
        STAGE(0, it + 2);
        MFMAS_KS(1);                            // overlaps staging issue

        // window `it+1` in buf1
        WAIT_NC();
        __builtin_amdgcn_s_barrier();
        __builtin_amdgcn_sched_barrier(0);
        LOADFRAGS(1);
        LGKM_HALF();
        __builtin_amdgcn_sched_barrier(0);
        MFMAS_KS(0);
        asm volatile("s_waitcnt lgkmcnt(0)" ::: "memory");
        __builtin_amdgcn_sched_barrier(0);
        __builtin_amdgcn_s_barrier();           // all waves done reading buf1
        __builtin_amdgcn_sched_barrier(0);
        if (it + 3 < NIT) STAGE(BUFSZ, it + 3);
        MFMAS_KS(1);
    }

    // ---- peel window NIT-2 (buf0): nothing stages into buf0 afterwards ----
    WAIT_NC();
    __builtin_amdgcn_s_barrier();
    __builtin_amdgcn_sched_barrier(0);
    LOADFRAGS(0);
    LGKM_HALF();
    __builtin_amdgcn_sched_barrier(0);
    MFMAS_KS(0);
    asm volatile("s_waitcnt lgkmcnt(0)" ::: "memory");
    __builtin_amdgcn_sched_barrier(0);
    MFMAS_KS(1);

    // ---- peel window NIT-1 (buf1) ----
    asm volatile("s_waitcnt vmcnt(0)" ::: "memory");
    __builtin_amdgcn_s_barrier();
    __builtin_amdgcn_sched_barrier(0);
    LOADFRAGS(1);
    LGKM_HALF();
    __builtin_amdgcn_sched_barrier(0);
    MFMAS_KS(0);
    asm volatile("s_waitcnt lgkmcnt(0)" ::: "memory");
    __builtin_amdgcn_sched_barrier(0);
    MFMAS_KS(1);

    if constexpr (SPLIT) {
        // ---- pair combine through LDS (reuse staging space) ----
        __syncthreads();
        if (pair == 1) {
#pragma unroll
            for (int mi = 0; mi < 4; ++mi)
#pragma unroll
                for (int ni = 0; ni < 4; ++ni)
                    *(i32x4*)&smem[nh * 16384 + (mi * 4 + ni) * 1024 + lane * 16] = acc[mi][ni];
        }
        __syncthreads();
        if (pair == 1) return;
#pragma unroll
        for (int mi = 0; mi < 4; ++mi)
#pragma unroll
            for (int ni = 0; ni < 4; ++ni) {
                const i32x4 other = *(const i32x4*)&smem[nh * 16384 + (mi * 4 + ni) * 1024 + lane * 16];
                acc[mi][ni] = acc[mi][ni] * 128 + other;   // 128*hi + lo
            }
    }

    // ---- epilogue: dequant, add quantized bias, act fake-quant ----
    float alpha = (*wmax) * (1.0f / 127.0f);
    if (FINAL) alpha *= *s_pre;      // conv2: acc * (s_a1 * s_w2)
    if (SPLIT) alpha *= XQ_DELTA;    // conv1: fixed-point dequant
    const float sact = *s_act;

    float bv[NB];
#pragma unroll
    for (int ni = 0; ni < NB; ++ni)
        bv[ni] = bias[n0 + nfix + ni * 16 + l16];

#pragma unroll
    for (int mi = 0; mi < 4; ++mi) {
#pragma unroll
        for (int i = 0; i < 4; ++i) {
            const int m = m0 + mi * 16 + quad * 4 + i;   // D row = quad*4+i
            const int b = m / HW;
            const int rem = m - b * HW;
            const int oh = rem / HOUT;
            const int ow = rem - oh * HOUT;
#pragma unroll
            for (int ni = 0; ni < NB; ++ni) {
                const int col = n0 + nfix + ni * 16 + l16;   // D col = l16
                const float v = (float)acc[mi][ni][i] * alpha + bv[ni];
                float q = rintf(v / sact);
                q = fminf(fmaxf(q, -128.0f), 127.0f);
                if (FINAL) {
                    out_final[(b * 512 + col) * HW + oh * HOUT + ow] = q * sact;
                } else {
                    act_out[(b * 256 + (oh + 1) * 16 + (ow + 1)) * 512 + col] = (signed char)(int)q;
                }
            }
        }
    }
}

// ---------------- launch ----------------
extern "C" void kernel_launch(void* const* d_in, const int* in_sizes, int n_in,
                              void* d_out, int out_size, void* d_ws, size_t ws_size,
                              hipStream_t stream) {
    const float* x  = (const float*)d_in[0];   // 64x256x28x28
    const float* w1 = (const float*)d_in[1];   // 512x256x3x3
    const float* b1 = (const float*)d_in[2];   // 512
    const float* w2 = (const float*)d_in[3];   // 512x512x3x3
    const float* b2 = (const float*)d_in[4];   // 512
    const float* in_scale   = (const float*)d_in[5];
    const float* act1_scale = (const float*)d_in[6];
    const float* act2_scale = (const float*)d_in[7];
    float* out = (float*)d_out;                // 64x512x14x14 NCHW fp32

    char* ws = (char*)d_ws;
    float* part = (float*)(ws + 0);                     // 512 floats
    float* wmax = (float*)(ws + 2048);                  // 2 floats
    float* bq1 = (float*)(ws + 2176);                   // 512 f
    float* bq2 = (float*)(ws + 4224);                   // 512 f
    signed char* wq1 = (signed char*)(ws + 8192);       // 512*2304 = 1,179,648
    signed char* wq2 = (signed char*)(ws + 1187840);    // 512*4608 = 2,359,296
    signed char* xhi = (signed char*)(ws + 3547136);    // 64*900*256 = 14,745,600
    signed char* xlo = (signed char*)(ws + 18292736);   // 14,745,600
    signed char* act = (signed char*)(ws + 33038336);   // 64*256*512 = 8,388,608 -> ends 41,426,944

    // dispatch 1: absmax partials + halos + x transform (independent work fused)
    fused_pre_kernel<<<4656, 256, 0, stream>>>(x, w1, w2, part, xhi, xlo, act);

    // dispatch 2: weight quant+transpose + bias quant + wmax (depends on partials)
    prep_w_kernel<<<1025, 256, 0, stream>>>(w1, w2, b1, b2, part, in_scale, act1_scale,
                                            wq1, wq2, bq1, bq2, wmax);

    // conv1: 256->512, s2, padded 30x30 in, hi/lo limb pairs, padded act codes out
    conv_gemm_kernel<256, 2, 30, 14, true, false><<<dim3(4, 196), 256, 0, stream>>>(
        xhi, xlo, wq1, bq1, wmax, act1_scale, act1_scale, act, nullptr);

    // conv2: 512->512, s1, padded 16x16 in (exact i8 codes), full-K per wave, fp32 NCHW out
    conv_gemm_kernel<512, 1, 16, 14, false, true><<<dim3(4, 196), 256, 0, stream>>>(
        act, nullptr, wq2, bq2, wmax + 1, act1_scale, act2_scale, nullptr, out);
}

// Round 14
// 222.164 us; speedup vs baseline: 1.5589x; 1.0083x over previous
//
#include <hip/hip_runtime.h>

typedef int i32x4 __attribute__((ext_vector_type(4)));

// async 16B global->LDS (wave-uniform LDS base; HW scatters lane*16)
__device__ __forceinline__ void gl_lds16(const signed char* g, signed char* l) {
    __builtin_amdgcn_global_load_lds(
        (const __attribute__((address_space(1))) void*)g,
        (__attribute__((address_space(3))) void*)l, 16, 0, 0);
}

// LDS byte address (32-bit) of a __shared__ pointer — precomputed once, kept in VGPR.
__device__ __forceinline__ unsigned lds_addr(const signed char* p) {
    return (unsigned)(uintptr_t)(const __attribute__((address_space(3))) signed char*)p;
}

// inline-asm LDS read from a precomputed address (rule #18: consume only after
// asm lgkmcnt + sched_barrier).
__device__ __forceinline__ i32x4 lds_read_b128a(unsigned a) {
    i32x4 r;
    asm volatile("ds_read_b128 %0, %1" : "=v"(r) : "v"(a));
    return r;
}

#define XQ_SCALE 2048.0f
#define XQ_DELTA (1.0f / 2048.0f)

// reduce 256 partials to a block-wide max (all 256 threads participate)
__device__ __forceinline__ float block_max256(const float* __restrict__ part, int base,
                                              float* __restrict__ sred) {
    float m = part[base + (threadIdx.x & 255)];
#pragma unroll
    for (int off = 32; off > 0; off >>= 1)
        m = fmaxf(m, __shfl_down(m, off));
    __syncthreads();
    if ((threadIdx.x & 63) == 0) sred[threadIdx.x >> 6] = m;
    __syncthreads();
    return fmaxf(fmaxf(sred[0], sred[1]), fmaxf(sred[2], sred[3]));
}

// ---------------- dispatch 1: absmax partials + halos + x transform ----------------
// Transform = R8's direct scalar form (best measured rump). R12 lesson: do NOT merge
// prep here via device-scope spin-sync (cross-XCD spin cost ~100µs).
__global__ __launch_bounds__(256) void fused_pre_kernel(
    const float* __restrict__ x,
    const float* __restrict__ w1, const float* __restrict__ w2,
    float* __restrict__ part,
    signed char* __restrict__ xhi, signed char* __restrict__ xlo,
    signed char* __restrict__ act) {
    __shared__ float sred[4];
    const int blk = blockIdx.x;
    const int tid = threadIdx.x;
    const uint4 z = {0, 0, 0, 0};

    if (blk < 512) {                       // ---- absmax partials
        const bool second = blk >= 256;
        const float* w = second ? w2 : w1;
        const int n4 = second ? 589824 : 294912;   // elements/4
        float m = 0.0f;
        for (int i = (blk & 255) * 256 + tid; i < n4; i += 65536) {
            float4 v = ((const float4*)w)[i];
            m = fmaxf(m, fmaxf(fmaxf(fabsf(v.x), fabsf(v.y)), fmaxf(fabsf(v.z), fabsf(v.w))));
        }
#pragma unroll
        for (int off = 32; off > 0; off >>= 1)
            m = fmaxf(m, __shfl_down(m, off));
        if ((tid & 63) == 0) sred[tid >> 6] = m;
        __syncthreads();
        if (tid == 0)
            part[blk] = fmaxf(fmaxf(sred[0], sred[1]), fmaxf(sred[2], sred[3]));
    } else if (blk < 976) {                // ---- x halo
        const int thr = (blk - 512) * 256 + tid;   // < 64*116*16 = 118784
        const int b = thr / (116 * 16);
        const int rr = thr - b * (116 * 16);
        const int p = rr >> 4;
        const int ch = rr & 15;
        int h, w;
        if (p < 30)      { h = 0;          w = p; }
        else if (p < 60) { h = 29;         w = p - 30; }
        else if (p < 88) { h = p - 60 + 1; w = 0; }
        else             { h = p - 88 + 1; w = 29; }
        const int off = (b * 900 + h * 30 + w) * 256 + ch * 16;
        *(uint4*)(xhi + off) = z;
        *(uint4*)(xlo + off) = z;
    } else if (blk < 1456) {               // ---- act halo
        const int thr = (blk - 976) * 256 + tid;   // < 64*60*32 = 122880
        const int b = thr / (60 * 32);
        const int rr = thr - b * (60 * 32);
        const int p = rr >> 5;
        const int ch = rr & 31;
        int h, w;
        if (p < 16)      { h = 0;          w = p; }
        else if (p < 32) { h = 15;         w = p - 16; }
        else if (p < 46) { h = p - 32 + 1; w = 0; }
        else             { h = p - 46 + 1; w = 15; }
        const int off = (b * 256 + h * 16 + w) * 512 + ch * 16;
        *(uint4*)(act + off) = z;
    } else {                               // ---- x transform (direct, no LDS)
        const int xb = blk - 1456;         // < 3200
        const int hwb = xb % 25;
        const int rest = xb / 25;
        const int cb = rest & 1;
        const int b = rest >> 1;
        const int c0 = cb * 128 + (tid >> 5) * 16;   // this thread's 16-channel group
        const int hw = hwb * 32 + (tid & 31);
        if (hw < 784) {
            const float* xp = x + (b * 256 + c0) * 784 + hw;
            union { signed char c[16]; uint4 u; } ph, pl;
#pragma unroll
            for (int j = 0; j < 16; ++j) {
                const float v = xp[j * 784];
                int q = (int)rintf(v * XQ_SCALE);
                q = max(-16383, min(16383, q));
                ph.c[j] = (signed char)(q >> 7);     // [-128,127]
                pl.c[j] = (signed char)(q & 127);    // [0,127]; q == 128*qh + ql
            }
            const int r = hw / 28;
            const int o = (b * 900 + (r + 1) * 30 + (hw - r * 28) + 1) * 256 + c0;
            *(uint4*)&xhi[o] = ph.u;
            *(uint4*)&xlo[o] = pl.u;
        }
    }
}

// ---------------- dispatch 2: weight quant+transpose, bias quant, wmax ----------------
// (R6: float4 weight reads; kept verbatim.)
__global__ __launch_bounds__(256) void prep_w_kernel(
    const float* __restrict__ w1, const float* __restrict__ w2,
    const float* __restrict__ b1, const float* __restrict__ b2,
    const float* __restrict__ part,
    const float* __restrict__ in_scale, const float* __restrict__ act1_scale,
    signed char* __restrict__ wq1, signed char* __restrict__ wq2,
    float* __restrict__ bq1, float* __restrict__ bq2,
    float* __restrict__ wmax) {
    __shared__ __align__(16) signed char sw[4608];
    __shared__ float sred[4];
    const int blk = blockIdx.x;
    const int tid = threadIdx.x;

    if (blk < 512) {                       // ---- w1 quant+transpose
        const float inv_s = 127.0f / block_max256(part, 0, sred);
        const int n = blk;
        const float4* src = (const float4*)(w1 + n * 2304);
#pragma unroll
        for (int rd = 0; rd < 3; ++rd) {
            const int f = rd * 256 + tid;              // float4 index < 576
            if (f < 576) {
                const float4 v = src[f];
                float q0 = fminf(fmaxf(rintf(v.x * inv_s), -127.0f), 127.0f);
                float q1 = fminf(fmaxf(rintf(v.y * inv_s), -127.0f), 127.0f);
                float q2 = fminf(fmaxf(rintf(v.z * inv_s), -127.0f), 127.0f);
                float q3 = fminf(fmaxf(rintf(v.w * inv_s), -127.0f), 127.0f);
                const int i0 = f * 4;
                int cin, r;
                cin = i0 / 9;       r = i0 - cin * 9;       sw[r * 256 + cin] = (signed char)(int)q0;
                cin = (i0+1) / 9;   r = (i0+1) - cin * 9;   sw[r * 256 + cin] = (signed char)(int)q1;
                cin = (i0+2) / 9;   r = (i0+2) - cin * 9;   sw[r * 256 + cin] = (signed char)(int)q2;
                cin = (i0+3) / 9;   r = (i0+3) - cin * 9;   sw[r * 256 + cin] = (signed char)(int)q3;
            }
        }
        __syncthreads();
        if (tid < 144) *(uint4*)&wq1[n * 2304 + tid * 16] = *(const uint4*)&sw[tid * 16];
    } else if (blk < 1024) {               // ---- w2 quant+transpose
        const float inv_s = 127.0f / block_max256(part, 256, sred);
        const int n = blk - 512;
        const float4* src = (const float4*)(w2 + n * 4608);
#pragma unroll
        for (int rd = 0; rd < 5; ++rd) {
            const int f = rd * 256 + tid;              // float4 index < 1152
            if (f < 1152) {
                const float4 v = src[f];
                float q0 = fminf(fmaxf(rintf(v.x * inv_s), -127.0f), 127.0f);
                float q1 = fminf(fmaxf(rintf(v.y * inv_s), -127.0f), 127.0f);
                float q2 = fminf(fmaxf(rintf(v.z * inv_s), -127.0f), 127.0f);
                float q3 = fminf(fmaxf(rintf(v.w * inv_s), -127.0f), 127.0f);
                const int i0 = f * 4;
                int cin, r;
                cin = i0 / 9;       r = i0 - cin * 9;       sw[r * 512 + cin] = (signed char)(int)q0;
                cin = (i0+1) / 9;   r = (i0+1) - cin * 9;   sw[r * 512 + cin] = (signed char)(int)q1;
                cin = (i0+2) / 9;   r = (i0+2) - cin * 9;   sw[r * 512 + cin] = (signed char)(int)q2;
                cin = (i0+3) / 9;   r = (i0+3) - cin * 9;   sw[r * 512 + cin] = (signed char)(int)q3;
            }
        }
        __syncthreads();
        for (int o = tid; o < 288; o += 256)
            *(uint4*)&wq2[n * 4608 + o * 16] = *(const uint4*)&sw[o * 16];
    } else {                               // ---- bias quant + wmax
        const float m1 = block_max256(part, 0, sred);
        const float m2 = block_max256(part, 256, sred);
        if (tid == 0) { wmax[0] = m1; wmax[1] = m2; }
        for (int idx = tid; idx < 1024; idx += 256) {
            if (idx < 512) {
                const float s = (*in_scale) * (m1 * (1.0f / 127.0f));
                float q = rintf(b1[idx] / s);
                q = fminf(fmaxf(q, -2147483648.0f), 2147483648.0f);
                bq1[idx] = q * s;
            } else {
                const int j = idx - 512;
                const float s = (*act1_scale) * (m2 * (1.0f / 127.0f));
                float q = rintf(b2[j] / s);
                q = fminf(fmaxf(q, -2147483648.0f), 2147483648.0f);
                bq2[j] = q * s;
            }
        }
    }
}

// ---------------- implicit-GEMM conv, i8 MFMA, 64m x 64n block, 4 waves ---------------
// NEW (this round): occupancy probe. Block n-tile 128 -> 64 shrinks LDS buffers so more
// blocks fit per CU (session evidence: occupancy monotone helps — R3's 6 waves/CU = 67µs,
// R2/R7's 12 = 60µs):
//   conv2 (!SPLIT): A 8K | B 8K = 16KB x2 = 32KB -> 5 blocks/CU (20 waves, was 12).
//                   Wave = 32m x 32n: pair=wv>>1 picks m-half, nh=wv&1 picks n-half;
//                   acc[2][2], 8 frag reads, 8 MFMA/window.
//   conv1 (SPLIT):  Ahi 8K | Alo 8K | B 8K = 24KB x2 = 48KB -> 3 blocks/CU (12 waves,
//                   was 8). Pair p = limb p; waves in pair split n 2x32: wave 64m x 32n,
//                   acc[4][2], 12 frag reads, 16 MFMA/window. LDS combine as before.
// Pipeline (R7, unchanged): counted-vmcnt, fine intra-window interleave, precomputed
// LDS addresses. Grid 1568 = dim3(8,196); T1 bijective swizzle (1568%8==0, chunks of
// 196; consecutive slots share the m-tile's A across 8 n-blocks on one XCD).
template<int CIN, int STRIDE, int HP, int HOUT, bool SPLIT, bool FINAL>
__global__ __launch_bounds__(256, SPLIT ? 3 : 5) void conv_gemm_kernel(
    const signed char* __restrict__ Ahi,
    const signed char* __restrict__ Alo,
    const signed char* __restrict__ Wt,
    const float* __restrict__ bias,
    const float* __restrict__ wmax,
    const float* __restrict__ s_pre,
    const float* __restrict__ s_act,
    signed char* __restrict__ act_out,  // !FINAL: padded NHWC i8 codes [64][16][16][512]
    float* __restrict__ out_final)      // FINAL: NCHW fp32
{
    constexpr int K = 9 * CIN;
    constexpr int HW = HOUT * HOUT;
    constexpr int NIT = K / 128;                  // windows: 18 (conv1) / 36 (conv2), even
    constexpr int NC = SPLIT ? 6 : 4;             // staging chunks per wave per window
    constexpr int BUFSZ = SPLIT ? 24576 : 16384;  // one buffer set
    constexpr int MA = SPLIT ? 4 : 2;             // m-fragments per wave

    __shared__ __align__(16) signed char smem[2 * BUFSZ];

    const int tid = threadIdx.x;
    const int lane = tid & 63;
    const int wv = tid >> 6;            // 0..3
    const int pair = wv >> 1;           // SPLIT: limb; !SPLIT: m-half
    const int nh = wv & 1;              // n-half (32 cols) within 64n tile
    const int quad = lane >> 4;
    const int l16 = lane & 15;

    // ---- XCD-aware bijective chunked swizzle (1568 blocks, 1568 % 8 == 0) ----
    const int lin = blockIdx.x + (int)gridDim.x * blockIdx.y;    // 0..1567
    const int swz = (lin & 7) * 196 + (lin >> 3);                // chunk of 196 per XCD
    const int n0 = (swz & 7) * 64;
    const int m0 = (swz >> 3) * 64;

    // staging: chunk = 1KB = 8 rows x 128B; lane -> (row lane>>3, phys slot lane&7)
    const int lrow = lane >> 3;
    const int koff = ((lane & 7) ^ lrow) * 16;   // swizzled logical k-offset

    const signed char* srcb[NC];
    int dsto[NC];
    bool isA[NC];
    if constexpr (SPLIT) {
        // 24 chunks: 0..7 A-hi, 8..15 A-lo, 16..23 B. Wave takes g = wv*6+i.
#pragma unroll
        for (int i = 0; i < NC; ++i) {
            const int g = wv * 6 + i;
            const int type = g >> 3;        // 0=A-hi, 1=A-lo, 2=B
            if (type == 2) {
                const int c = g - 16;
                srcb[i] = Wt + (n0 + c * 8 + lrow) * K + koff;
                dsto[i] = 16384 + c * 1024;
                isA[i] = false;
            } else {
                const int c = g & 7;
                const int m = m0 + c * 8 + lrow;
                const int b = m / HW;
                const int rem = m - b * HW;
                const int oh = rem / HOUT;
                const int ow = rem - oh * HOUT;
                const int off = ((b * HP + oh * STRIDE) * HP + ow * STRIDE) * CIN + koff;
                srcb[i] = (type == 0 ? Ahi : Alo) + off;
                dsto[i] = type * 8192 + c * 1024;
                isA[i] = true;
            }
        }
    } else {
        // 16 chunks: 0..7 A, 8..15 B. Wave takes g = wv*4+i.
#pragma unroll
        for (int i = 0; i < NC; ++i) {
            const int g = wv * 4 + i;
            if (g < 8) {
                const int c = g;
                const int m = m0 + c * 8 + lrow;
                const int b = m / HW;
                const int rem = m - b * HW;
                const int oh = rem / HOUT;
                const int ow = rem - oh * HOUT;
                const int off = ((b * HP + oh * STRIDE) * HP + ow * STRIDE) * CIN + koff;
                srcb[i] = Ahi + off;
                dsto[i] = c * 1024;
                isA[i] = true;
            } else {
                const int c = g - 8;
                srcb[i] = Wt + (n0 + c * 8 + lrow) * K + koff;
                dsto[i] = 8192 + c * 1024;
                isA[i] = false;
            }
        }
    }

    const int aoff0 = SPLIT ? (pair * 8192) : 0;     // limb region (SPLIT) / A base
    const int boff0 = SPLIT ? 16384 : 8192;
    const int mrow0 = SPLIT ? 0 : (pair * 32);       // wave's m-offset within 64
    const int nfix  = nh * 32;                       // wave's n-offset within 64

    // ---- precomputed LDS read addresses: [buf][ks][frag] ----
    unsigned aad[2][2][MA];
    unsigned bad[2][2][2];
#pragma unroll
    for (int bi = 0; bi < 2; ++bi)
#pragma unroll
        for (int ks = 0; ks < 2; ++ks) {
#pragma unroll
            for (int mi = 0; mi < MA; ++mi) {
                const int row = mrow0 + mi * 16 + l16;
                const int sl = ((ks * 4 + quad) ^ (row & 7)) * 16;
                aad[bi][ks][mi] = lds_addr(&smem[bi * BUFSZ + aoff0 + row * 128 + sl]);
            }
#pragma unroll
            for (int ni = 0; ni < 2; ++ni) {
                const int row = nfix + ni * 16 + l16;
                const int sl = ((ks * 4 + quad) ^ (row & 7)) * 16;
                bad[bi][ks][ni] = lds_addr(&smem[bi * BUFSZ + boff0 + row * 128 + sl]);
            }
        }

    i32x4 acc[MA][2];
#pragma unroll
    for (int mi = 0; mi < MA; ++mi)
#pragma unroll
        for (int ni = 0; ni < 2; ++ni)
            acc[mi][ni] = i32x4{0, 0, 0, 0};

    // issue this wave's NC chunks for window `it` into buffer at byte offset `bo`
    auto STAGE = [&](int bo, int it) {
        const int k0 = it * 128;
        const int r9 = k0 / CIN;            // wave-uniform
        const int kh = r9 / 3;
        const int kw = r9 - kh * 3;
        const int ashift = (kh * HP + kw) * CIN + (k0 & (CIN - 1));
#pragma unroll
        for (int i = 0; i < NC; ++i)
            gl_lds16(srcb[i] + (isA[i] ? ashift : k0), &smem[bo + dsto[i]]);
    };

    i32x4 af[2][MA], bf[2][2];

    // pure ds_read issue from precomputed addresses (ks0 first -> counted lgkm gates ks0)
    auto LOADFRAGS = [&](int bi) {
#pragma unroll
        for (int ks = 0; ks < 2; ++ks) {
#pragma unroll
            for (int mi = 0; mi < MA; ++mi)
                af[ks][mi] = lds_read_b128a(aad[bi][ks][mi]);
#pragma unroll
            for (int ni = 0; ni < 2; ++ni)
                bf[ks][ni] = lds_read_b128a(bad[bi][ks][ni]);
        }
    };

    auto MFMAS_KS = [&](int ks) {
        __builtin_amdgcn_s_setprio(1);
#pragma unroll
        for (int mi = 0; mi < MA; ++mi)
#pragma unroll
            for (int ni = 0; ni < 2; ++ni)
                acc[mi][ni] = __builtin_amdgcn_mfma_i32_16x16x64_i8(af[ks][mi], bf[ks][ni], acc[mi][ni], 0, 0, 0);
        __builtin_amdgcn_s_setprio(0);
    };

    auto WAIT_NC = [&]() {   // wait until only the newest NC loads remain in flight
        if constexpr (SPLIT) asm volatile("s_waitcnt vmcnt(6)" ::: "memory");
        else                 asm volatile("s_waitcnt vmcnt(4)" ::: "memory");
    };
    auto LGKM_HALF = [&]() { // ks0 frag reads landed; ks1's still in flight
        if constexpr (SPLIT) asm volatile("s_waitcnt lgkmcnt(6)" ::: "memory");
        else                 asm volatile("s_waitcnt lgkmcnt(4)" ::: "memory");
    };

    // ---- prologue: fill both buffers (2*NC loads in flight) ----
    STAGE(0, 0);
    STAGE(BUFSZ, 1);

    // ---- steady state: windows 0..NIT-3 ----
    for (int it = 0; it < NIT - 2; it += 2) {
        // window `it` in buf0
        WAIT_NC();
        __builtin_amdgcn_s_barrier();
        __builtin_amdgcn_sched_barrier(0);
        LOADFRAGS(0);
        LGKM_HALF();
        __builtin_amdgcn_sched_barrier(0);
        MFMAS_KS(0);                            // overlaps ks1 ds_reads
        asm volatile("s_waitcnt lgkmcnt(0)" ::: "memory");
        __builtin_amdgcn_sched_barrier(0);
        __builtin_amdgcn_s_barrier();           // all waves done reading buf0
        __builtin_amdgcn_sched_barrier(0);
        STAGE(0, it + 2);
        MFMAS_KS(1);                            // overlaps staging issue

        // window `it+1` in buf1
        WAIT_NC();
        __builtin_amdgcn_s_barrier();
        __builtin_amdgcn_sched_barrier(0);
        LOADFRAGS(1);
        LGKM_HALF();
        __builtin_amdgcn_sched_barrier(0);
        MFMAS_KS(0);
        asm volatile("s_waitcnt lgkmcnt(0)" ::: "memory");
        __builtin_amdgcn_sched_barrier(0);
        __builtin_amdgcn_s_barrier();           // all waves done reading buf1
        __builtin_amdgcn_sched_barrier(0);
        if (it + 3 < NIT) STAGE(BUFSZ, it + 3);
        MFMAS_KS(1);
    }

    // ---- peel window NIT-2 (buf0): nothing stages into buf0 afterwards ----
    WAIT_NC();
    __builtin_amdgcn_s_barrier();
    __builtin_amdgcn_sched_barrier(0);
    LOADFRAGS(0);
    LGKM_HALF();
    __builtin_amdgcn_sched_barrier(0);
    MFMAS_KS(0);
    asm volatile("s_waitcnt lgkmcnt(0)" ::: "memory");
    __builtin_amdgcn_sched_barrier(0);
    MFMAS_KS(1);

    // ---- peel window NIT-1 (buf1) ----
    asm volatile("s_waitcnt vmcnt(0)" ::: "memory");
    __builtin_amdgcn_s_barrier();
    __builtin_amdgcn_sched_barrier(0);
    LOADFRAGS(1);
    LGKM_HALF();
    __builtin_amdgcn_sched_barrier(0);
    MFMAS_KS(0);
    asm volatile("s_waitcnt lgkmcnt(0)" ::: "memory");
    __builtin_amdgcn_sched_barrier(0);
    MFMAS_KS(1);

    if constexpr (SPLIT) {
        // ---- pair combine through LDS (reuse staging space; 16KB total) ----
        __syncthreads();
        if (pair == 1) {
#pragma unroll
            for (int mi = 0; mi < 4; ++mi)
#pragma unroll
                for (int ni = 0; ni < 2; ++ni)
                    *(i32x4*)&smem[nh * 8192 + (mi * 2 + ni) * 1024 + lane * 16] = acc[mi][ni];
        }
        __syncthreads();
        if (pair == 1) return;
#pragma unroll
        for (int mi = 0; mi < 4; ++mi)
#pragma unroll
            for (int ni = 0; ni < 2; ++ni) {
                const i32x4 other = *(const i32x4*)&smem[nh * 8192 + (mi * 2 + ni) * 1024 + lane * 16];
                acc[mi][ni] = acc[mi][ni] * 128 + other;   // 128*hi + lo
            }
    }

    // ---- epilogue: dequant, add quantized bias, act fake-quant ----
    float alpha = (*wmax) * (1.0f / 127.0f);
    if (FINAL) alpha *= *s_pre;      // conv2: acc * (s_a1 * s_w2)
    if (SPLIT) alpha *= XQ_DELTA;    // conv1: fixed-point dequant
    const float sact = *s_act;

    float bv[2];
#pragma unroll
    for (int ni = 0; ni < 2; ++ni)
        bv[ni] = bias[n0 + nfix + ni * 16 + l16];

#pragma unroll
    for (int mi = 0; mi < MA; ++mi) {
#pragma unroll
        for (int i = 0; i < 4; ++i) {
            const int m = m0 + mrow0 + mi * 16 + quad * 4 + i;   // D row = quad*4+i
            const int b = m / HW;
            const int rem = m - b * HW;
            const int oh = rem / HOUT;
            const int ow = rem - oh * HOUT;
#pragma unroll
            for (int ni = 0; ni < 2; ++ni) {
                const int col = n0 + nfix + ni * 16 + l16;   // D col = l16
                const float v = (float)acc[mi][ni][i] * alpha + bv[ni];
                float q = rintf(v / sact);
                q = fminf(fmaxf(q, -128.0f), 127.0f);
                if (FINAL) {
                    out_final[(b * 512 + col) * HW + oh * HOUT + ow] = q * sact;
                } else {
                    act_out[(b * 256 + (oh + 1) * 16 + (ow + 1)) * 512 + col] = (signed char)(int)q;
                }
            }
        }
    }
}

// ---------------- launch ----------------
extern "C" void kernel_launch(void* const* d_in, const int* in_sizes, int n_in,
                              void* d_out, int out_size, void* d_ws, size_t ws_size,
                              hipStream_t stream) {
    const float* x  = (const float*)d_in[0];   // 64x256x28x28
    const float* w1 = (const float*)d_in[1];   // 512x256x3x3
    const float* b1 = (const float*)d_in[2];   // 512
    const float* w2 = (const float*)d_in[3];   // 512x512x3x3
    const float* b2 = (const float*)d_in[4];   // 512
    const float* in_scale   = (const float*)d_in[5];
    const float* act1_scale = (const float*)d_in[6];
    const float* act2_scale = (const float*)d_in[7];
    float* out = (float*)d_out;                // 64x512x14x14 NCHW fp32

    char* ws = (char*)d_ws;
    float* part = (float*)(ws + 0);                     // 512 floats
    float* wmax = (float*)(ws + 2048);                  // 2 floats
    float* bq1 = (float*)(ws + 2176);                   // 512 f
    float* bq2 = (float*)(ws + 4224);                   // 512 f
    signed char* wq1 = (signed char*)(ws + 8192);       // 512*2304 = 1,179,648
    signed char* wq2 = (signed char*)(ws + 1187840);    // 512*4608 = 2,359,296
    signed char* xhi = (signed char*)(ws + 3547136);    // 64*900*256 = 14,745,600
    signed char* xlo = (signed char*)(ws + 18292736);   // 14,745,600
    signed char* act = (signed char*)(ws + 33038336);   // 64*256*512 = 8,388,608 -> ends 41,426,944

    // dispatch 1: absmax partials + halos + x transform (independent work fused)
    fused_pre_kernel<<<4656, 256, 0, stream>>>(x, w1, w2, part, xhi, xlo, act);

    // dispatch 2: weight quant+transpose + bias quant + wmax (depends on partials)
    prep_w_kernel<<<1025, 256, 0, stream>>>(w1, w2, b1, b2, part, in_scale, act1_scale,
                                            wq1, wq2, bq1, bq2, wmax);

    // conv1: 256->512, s2, padded 30x30 in, hi/lo limb pairs, padded act codes out
    conv_gemm_kernel<256, 2, 30, 14, true, false><<<dim3(8, 196), 256, 0, stream>>>(
        xhi, xlo, wq1, bq1, wmax, act1_scale, act1_scale, act, nullptr);

    // conv2: 512->512, s1, padded 16x16 in (exact i8 codes), full-K per wave, fp32 NCHW out
    conv_gemm_kernel<512, 1, 16, 14, false, true><<<dim3(8, 196), 256, 0, stream>>>(
        act, nullptr, wq2, bq2, wmax + 1, act1_scale, act2_scale, nullptr, out);
}

// Round 15
// 218.506 us; speedup vs baseline: 1.5850x; 1.0167x over previous
//
#include <hip/hip_runtime.h>

typedef int i32x4 __attribute__((ext_vector_type(4)));

// async 16B global->LDS (wave-uniform LDS base; HW scatters lane*16)
__device__ __forceinline__ void gl_lds16(const signed char* g, signed char* l) {
    __builtin_amdgcn_global_load_lds(
        (const __attribute__((address_space(1))) void*)g,
        (__attribute__((address_space(3))) void*)l, 16, 0, 0);
}

// LDS byte address (32-bit) of a __shared__ pointer — precomputed once, kept in VGPR.
__device__ __forceinline__ unsigned lds_addr(const signed char* p) {
    return (unsigned)(uintptr_t)(const __attribute__((address_space(3))) signed char*)p;
}

// inline-asm LDS read from a precomputed address (rule #18: consume only after
// asm lgkmcnt + sched_barrier).
__device__ __forceinline__ i32x4 lds_read_b128a(unsigned a) {
    i32x4 r;
    asm volatile("ds_read_b128 %0, %1" : "=v"(r) : "v"(a));
    return r;
}

#define XQ_SCALE 2048.0f
#define XQ_DELTA (1.0f / 2048.0f)

// reduce 256 partials to a block-wide max (all 256 threads participate)
__device__ __forceinline__ float block_max256(const float* __restrict__ part, int base,
                                              float* __restrict__ sred) {
    float m = part[base + (threadIdx.x & 255)];
#pragma unroll
    for (int off = 32; off > 0; off >>= 1)
        m = fmaxf(m, __shfl_down(m, off));
    __syncthreads();
    if ((threadIdx.x & 63) == 0) sred[threadIdx.x >> 6] = m;
    __syncthreads();
    return fmaxf(fmaxf(sred[0], sred[1]), fmaxf(sred[2], sred[3]));
}

// ---------------- dispatch 1: absmax partials + halos + x transform ----------------
// NEW (this round): transform reads vectorized as float2 over hw (2 hw/thread, 8B/lane
// — G13 sweet spot; halves read-instruction count vs R8's scalar form) while keeping
// the per-hw 16B write pattern that R9's float4 variant broke. Numerics identical.
// R12 lesson kept: no prep merge via device-scope spin-sync (cross-XCD spin ~100µs).
__global__ __launch_bounds__(256) void fused_pre_kernel(
    const float* __restrict__ x,
    const float* __restrict__ w1, const float* __restrict__ w2,
    float* __restrict__ part,
    signed char* __restrict__ xhi, signed char* __restrict__ xlo,
    signed char* __restrict__ act) {
    __shared__ float sred[4];
    const int blk = blockIdx.x;
    const int tid = threadIdx.x;
    const uint4 z = {0, 0, 0, 0};

    if (blk < 512) {                       // ---- absmax partials
        const bool second = blk >= 256;
        const float* w = second ? w2 : w1;
        const int n4 = second ? 589824 : 294912;   // elements/4
        float m = 0.0f;
        for (int i = (blk & 255) * 256 + tid; i < n4; i += 65536) {
            float4 v = ((const float4*)w)[i];
            m = fmaxf(m, fmaxf(fmaxf(fabsf(v.x), fabsf(v.y)), fmaxf(fabsf(v.z), fabsf(v.w))));
        }
#pragma unroll
        for (int off = 32; off > 0; off >>= 1)
            m = fmaxf(m, __shfl_down(m, off));
        if ((tid & 63) == 0) sred[tid >> 6] = m;
        __syncthreads();
        if (tid == 0)
            part[blk] = fmaxf(fmaxf(sred[0], sred[1]), fmaxf(sred[2], sred[3]));
    } else if (blk < 976) {                // ---- x halo
        const int thr = (blk - 512) * 256 + tid;   // < 64*116*16 = 118784
        const int b = thr / (116 * 16);
        const int rr = thr - b * (116 * 16);
        const int p = rr >> 4;
        const int ch = rr & 15;
        int h, w;
        if (p < 30)      { h = 0;          w = p; }
        else if (p < 60) { h = 29;         w = p - 30; }
        else if (p < 88) { h = p - 60 + 1; w = 0; }
        else             { h = p - 88 + 1; w = 29; }
        const int off = (b * 900 + h * 30 + w) * 256 + ch * 16;
        *(uint4*)(xhi + off) = z;
        *(uint4*)(xlo + off) = z;
    } else if (blk < 1456) {               // ---- act halo
        const int thr = (blk - 976) * 256 + tid;   // < 64*60*32 = 122880
        const int b = thr / (60 * 32);
        const int rr = thr - b * (60 * 32);
        const int p = rr >> 5;
        const int ch = rr & 31;
        int h, w;
        if (p < 16)      { h = 0;          w = p; }
        else if (p < 32) { h = 15;         w = p - 16; }
        else if (p < 46) { h = p - 32 + 1; w = 0; }
        else             { h = p - 46 + 1; w = 15; }
        const int off = (b * 256 + h * 16 + w) * 512 + ch * 16;
        *(uint4*)(act + off) = z;
    } else {                               // ---- x transform (direct, float2 over hw)
        const int xb = blk - 1456;         // < 1664
        const int hwb = xb % 13;
        const int rest = xb / 13;
        const int cb = rest & 1;
        const int b = rest >> 1;
        const int c0 = cb * 128 + (tid >> 5) * 16;   // this thread's 16-channel group
        const int hw = hwb * 64 + (tid & 31) * 2;    // 2 consecutive hw (784 even)
        if (hw < 784) {                    // hw even -> hw and hw+1 both valid
            const float* xp = x + (b * 256 + c0) * 784 + hw;
            float2 v[16];
#pragma unroll
            for (int j = 0; j < 16; ++j)
                v[j] = *(const float2*)(xp + j * 784);
#pragma unroll
            for (int p = 0; p < 2; ++p) {
                union { signed char c[16]; uint4 u; } ph, pl;
#pragma unroll
                for (int j = 0; j < 16; ++j) {
                    const float val = p ? v[j].y : v[j].x;
                    int q = (int)rintf(val * XQ_SCALE);
                    q = max(-16383, min(16383, q));
                    ph.c[j] = (signed char)(q >> 7);     // [-128,127]
                    pl.c[j] = (signed char)(q & 127);    // [0,127]; q == 128*qh + ql
                }
                const int hwp = hw + p;
                const int r = hwp / 28;
                const int o = (b * 900 + (r + 1) * 30 + (hwp - r * 28) + 1) * 256 + c0;
                *(uint4*)&xhi[o] = ph.u;
                *(uint4*)&xlo[o] = pl.u;
            }
        }
    }
}

// ---------------- dispatch 2: weight quant+transpose, bias quant, wmax ----------------
// (R6: float4 weight reads; kept verbatim.)
__global__ __launch_bounds__(256) void prep_w_kernel(
    const float* __restrict__ w1, const float* __restrict__ w2,
    const float* __restrict__ b1, const float* __restrict__ b2,
    const float* __restrict__ part,
    const float* __restrict__ in_scale, const float* __restrict__ act1_scale,
    signed char* __restrict__ wq1, signed char* __restrict__ wq2,
    float* __restrict__ bq1, float* __restrict__ bq2,
    float* __restrict__ wmax) {
    __shared__ __align__(16) signed char sw[4608];
    __shared__ float sred[4];
    const int blk = blockIdx.x;
    const int tid = threadIdx.x;

    if (blk < 512) {                       // ---- w1 quant+transpose
        const float inv_s = 127.0f / block_max256(part, 0, sred);
        const int n = blk;
        const float4* src = (const float4*)(w1 + n * 2304);
#pragma unroll
        for (int rd = 0; rd < 3; ++rd) {
            const int f = rd * 256 + tid;              // float4 index < 576
            if (f < 576) {
                const float4 v = src[f];
                float q0 = fminf(fmaxf(rintf(v.x * inv_s), -127.0f), 127.0f);
                float q1 = fminf(fmaxf(rintf(v.y * inv_s), -127.0f), 127.0f);
                float q2 = fminf(fmaxf(rintf(v.z * inv_s), -127.0f), 127.0f);
                float q3 = fminf(fmaxf(rintf(v.w * inv_s), -127.0f), 127.0f);
                const int i0 = f * 4;
                int cin, r;
                cin = i0 / 9;       r = i0 - cin * 9;       sw[r * 256 + cin] = (signed char)(int)q0;
                cin = (i0+1) / 9;   r = (i0+1) - cin * 9;   sw[r * 256 + cin] = (signed char)(int)q1;
                cin = (i0+2) / 9;   r = (i0+2) - cin * 9;   sw[r * 256 + cin] = (signed char)(int)q2;
                cin = (i0+3) / 9;   r = (i0+3) - cin * 9;   sw[r * 256 + cin] = (signed char)(int)q3;
            }
        }
        __syncthreads();
        if (tid < 144) *(uint4*)&wq1[n * 2304 + tid * 16] = *(const uint4*)&sw[tid * 16];
    } else if (blk < 1024) {               // ---- w2 quant+transpose
        const float inv_s = 127.0f / block_max256(part, 256, sred);
        const int n = blk - 512;
        const float4* src = (const float4*)(w2 + n * 4608);
#pragma unroll
        for (int rd = 0; rd < 5; ++rd) {
            const int f = rd * 256 + tid;              // float4 index < 1152
            if (f < 1152) {
                const float4 v = src[f];
                float q0 = fminf(fmaxf(rintf(v.x * inv_s), -127.0f), 127.0f);
                float q1 = fminf(fmaxf(rintf(v.y * inv_s), -127.0f), 127.0f);
                float q2 = fminf(fmaxf(rintf(v.z * inv_s), -127.0f), 127.0f);
                float q3 = fminf(fmaxf(rintf(v.w * inv_s), -127.0f), 127.0f);
                const int i0 = f * 4;
                int cin, r;
                cin = i0 / 9;       r = i0 - cin * 9;       sw[r * 512 + cin] = (signed char)(int)q0;
                cin = (i0+1) / 9;   r = (i0+1) - cin * 9;   sw[r * 512 + cin] = (signed char)(int)q1;
                cin = (i0+2) / 9;   r = (i0+2) - cin * 9;   sw[r * 512 + cin] = (signed char)(int)q2;
                cin = (i0+3) / 9;   r = (i0+3) - cin * 9;   sw[r * 512 + cin] = (signed char)(int)q3;
            }
        }
        __syncthreads();
        for (int o = tid; o < 288; o += 256)
            *(uint4*)&wq2[n * 4608 + o * 16] = *(const uint4*)&sw[o * 16];
    } else {                               // ---- bias quant + wmax
        const float m1 = block_max256(part, 0, sred);
        const float m2 = block_max256(part, 256, sred);
        if (tid == 0) { wmax[0] = m1; wmax[1] = m2; }
        for (int idx = tid; idx < 1024; idx += 256) {
            if (idx < 512) {
                const float s = (*in_scale) * (m1 * (1.0f / 127.0f));
                float q = rintf(b1[idx] / s);
                q = fminf(fmaxf(q, -2147483648.0f), 2147483648.0f);
                bq1[idx] = q * s;
            } else {
                const int j = idx - 512;
                const float s = (*act1_scale) * (m2 * (1.0f / 127.0f));
                float q = rintf(b2[j] / s);
                q = fminf(fmaxf(q, -2147483648.0f), 2147483648.0f);
                bq2[j] = q * s;
            }
        }
    }
}

// ---------------- implicit-GEMM conv, i8 MFMA, 64m x 64n block, 4 waves ---------------
// R14 config kept (best-evidenced conv: 58.5µs, lowest resources). Conv declared at
// session floor: counted-vmcnt pipeline (R2, +12%) + T1 XCD swizzle (R11, FETCH 3x cut)
// are the only levers that paid across 9 structural probes; occupancy 18->28% was null.
template<int CIN, int STRIDE, int HP, int HOUT, bool SPLIT, bool FINAL>
__global__ __launch_bounds__(256, SPLIT ? 3 : 5) void conv_gemm_kernel(
    const signed char* __restrict__ Ahi,
    const signed char* __restrict__ Alo,
    const signed char* __restrict__ Wt,
    const float* __restrict__ bias,
    const float* __restrict__ wmax,
    const float* __restrict__ s_pre,
    const float* __restrict__ s_act,
    signed char* __restrict__ act_out,  // !FINAL: padded NHWC i8 codes [64][16][16][512]
    float* __restrict__ out_final)      // FINAL: NCHW fp32
{
    constexpr int K = 9 * CIN;
    constexpr int HW = HOUT * HOUT;
    constexpr int NIT = K / 128;                  // windows: 18 (conv1) / 36 (conv2), even
    constexpr int NC = SPLIT ? 6 : 4;             // staging chunks per wave per window
    constexpr int BUFSZ = SPLIT ? 24576 : 16384;  // one buffer set
    constexpr int MA = SPLIT ? 4 : 2;             // m-fragments per wave

    __shared__ __align__(16) signed char smem[2 * BUFSZ];

    const int tid = threadIdx.x;
    const int lane = tid & 63;
    const int wv = tid >> 6;            // 0..3
    const int pair = wv >> 1;           // SPLIT: limb; !SPLIT: m-half
    const int nh = wv & 1;              // n-half (32 cols) within 64n tile
    const int quad = lane >> 4;
    const int l16 = lane & 15;

    // ---- XCD-aware bijective chunked swizzle (1568 blocks, 1568 % 8 == 0) ----
    const int lin = blockIdx.x + (int)gridDim.x * blockIdx.y;    // 0..1567
    const int swz = (lin & 7) * 196 + (lin >> 3);                // chunk of 196 per XCD
    const int n0 = (swz & 7) * 64;
    const int m0 = (swz >> 3) * 64;

    // staging: chunk = 1KB = 8 rows x 128B; lane -> (row lane>>3, phys slot lane&7)
    const int lrow = lane >> 3;
    const int koff = ((lane & 7) ^ lrow) * 16;   // swizzled logical k-offset

    const signed char* srcb[NC];
    int dsto[NC];
    bool isA[NC];
    if constexpr (SPLIT) {
        // 24 chunks: 0..7 A-hi, 8..15 A-lo, 16..23 B. Wave takes g = wv*6+i.
#pragma unroll
        for (int i = 0; i < NC; ++i) {
            const int g = wv * 6 + i;
            const int type = g >> 3;        // 0=A-hi, 1=A-lo, 2=B
            if (type == 2) {
                const int c = g - 16;
                srcb[i] = Wt + (n0 + c * 8 + lrow) * K + koff;
                dsto[i] = 16384 + c * 1024;
                isA[i] = false;
            } else {
                const int c = g & 7;
                const int m = m0 + c * 8 + lrow;
                const int b = m / HW;
                const int rem = m - b * HW;
                const int oh = rem / HOUT;
                const int ow = rem - oh * HOUT;
                const int off = ((b * HP + oh * STRIDE) * HP + ow * STRIDE) * CIN + koff;
                srcb[i] = (type == 0 ? Ahi : Alo) + off;
                dsto[i] = type * 8192 + c * 1024;
                isA[i] = true;
            }
        }
    } else {
        // 16 chunks: 0..7 A, 8..15 B. Wave takes g = wv*4+i.
#pragma unroll
        for (int i = 0; i < NC; ++i) {
            const int g = wv * 4 + i;
            if (g < 8) {
                const int c = g;
                const int m = m0 + c * 8 + lrow;
                const int b = m / HW;
                const int rem = m - b * HW;
                const int oh = rem / HOUT;
                const int ow = rem - oh * HOUT;
                const int off = ((b * HP + oh * STRIDE) * HP + ow * STRIDE) * CIN + koff;
                srcb[i] = Ahi + off;
                dsto[i] = c * 1024;
                isA[i] = true;
            } else {
                const int c = g - 8;
                srcb[i] = Wt + (n0 + c * 8 + lrow) * K + koff;
                dsto[i] = 8192 + c * 1024;
                isA[i] = false;
            }
        }
    }

    const int aoff0 = SPLIT ? (pair * 8192) : 0;     // limb region (SPLIT) / A base
    const int boff0 = SPLIT ? 16384 : 8192;
    const int mrow0 = SPLIT ? 0 : (pair * 32);       // wave's m-offset within 64
    const int nfix  = nh * 32;                       // wave's n-offset within 64

    // ---- precomputed LDS read addresses: [buf][ks][frag] ----
    unsigned aad[2][2][MA];
    unsigned bad[2][2][2];
#pragma unroll
    for (int bi = 0; bi < 2; ++bi)
#pragma unroll
        for (int ks = 0; ks < 2; ++ks) {
#pragma unroll
            for (int mi = 0; mi < MA; ++mi) {
                const int row = mrow0 + mi * 16 + l16;
                const int sl = ((ks * 4 + quad) ^ (row & 7)) * 16;
                aad[bi][ks][mi] = lds_addr(&smem[bi * BUFSZ + aoff0 + row * 128 + sl]);
            }
#pragma unroll
            for (int ni = 0; ni < 2; ++ni) {
                const int row = nfix + ni * 16 + l16;
                const int sl = ((ks * 4 + quad) ^ (row & 7)) * 16;
                bad[bi][ks][ni] = lds_addr(&smem[bi * BUFSZ + boff0 + row * 128 + sl]);
            }
        }

    i32x4 acc[MA][2];
#pragma unroll
    for (int mi = 0; mi < MA; ++mi)
#pragma unroll
        for (int ni = 0; ni < 2; ++ni)
            acc[mi][ni] = i32x4{0, 0, 0, 0};

    // issue this wave's NC chunks for window `it` into buffer at byte offset `bo`
    auto STAGE = [&](int bo, int it) {
        const int k0 = it * 128;
        const int r9 = k0 / CIN;            // wave-uniform
        const int kh = r9 / 3;
        const int kw = r9 - kh * 3;
        const int ashift = (kh * HP + kw) * CIN + (k0 & (CIN - 1));
#pragma unroll
        for (int i = 0; i < NC; ++i)
            gl_lds16(srcb[i] + (isA[i] ? ashift : k0), &smem[bo + dsto[i]]);
    };

    i32x4 af[2][MA], bf[2][2];

    // pure ds_read issue from precomputed addresses (ks0 first -> counted lgkm gates ks0)
    auto LOADFRAGS = [&](int bi) {
#pragma unroll
        for (int ks = 0; ks < 2; ++ks) {
#pragma unroll
            for (int mi = 0; mi < MA; ++mi)
                af[ks][mi] = lds_read_b128a(aad[bi][ks][mi]);
#pragma unroll
            for (int ni = 0; ni < 2; ++ni)
                bf[ks][ni] = lds_read_b128a(bad[bi][ks][ni]);
        }
    };

    auto MFMAS_KS = [&](int ks) {
        __builtin_amdgcn_s_setprio(1);
#pragma unroll
        for (int mi = 0; mi < MA; ++mi)
#pragma unroll
            for (int ni = 0; ni < 2; ++ni)
                acc[mi][ni] = __builtin_amdgcn_mfma_i32_16x16x64_i8(af[ks][mi], bf[ks][ni], acc[mi][ni], 0, 0, 0);
        __builtin_amdgcn_s_setprio(0);
    };

    auto WAIT_NC = [&]() {   // wait until only the newest NC loads remain in flight
        if constexpr (SPLIT) asm volatile("s_waitcnt vmcnt(6)" ::: "memory");
        else                 asm volatile("s_waitcnt vmcnt(4)" ::: "memory");
    };
    auto LGKM_HALF = [&]() { // ks0 frag reads landed; ks1's still in flight
        if constexpr (SPLIT) asm volatile("s_waitcnt lgkmcnt(6)" ::: "memory");
        else                 asm volatile("s_waitcnt lgkmcnt(4)" ::: "memory");
    };

    // ---- prologue: fill both buffers (2*NC loads in flight) ----
    STAGE(0, 0);
    STAGE(BUFSZ, 1);

    // ---- steady state: windows 0..NIT-3 ----
    for (int it = 0; it < NIT - 2; it += 2) {
        // window `it` in buf0
        WAIT_NC();
        __builtin_amdgcn_s_barrier();
        __builtin_amdgcn_sched_barrier(0);
        LOADFRAGS(0);
        LGKM_HALF();
        __builtin_amdgcn_sched_barrier(0);
        MFMAS_KS(0);                            // overlaps ks1 ds_reads
        asm volatile("s_waitcnt lgkmcnt(0)" ::: "memory");
        __builtin_amdgcn_sched_barrier(0);
        __builtin_amdgcn_s_barrier();           // all waves done reading buf0
        __builtin_amdgcn_sched_barrier(0);
        STAGE(0, it + 2);
        MFMAS_KS(1);                            // overlaps staging issue

        // window `it+1` in buf1
        WAIT_NC();
        __builtin_amdgcn_s_barrier();
        __builtin_amdgcn_sched_barrier(0);
        LOADFRAGS(1);
        LGKM_HALF();
        __builtin_amdgcn_sched_barrier(0);
        MFMAS_KS(0);
        asm volatile("s_waitcnt lgkmcnt(0)" ::: "memory");
        __builtin_amdgcn_sched_barrier(0);
        __builtin_amdgcn_s_barrier();           // all waves done reading buf1
        __builtin_amdgcn_sched_barrier(0);
        if (it + 3 < NIT) STAGE(BUFSZ, it + 3);
        MFMAS_KS(1);
    }

    // ---- peel window NIT-2 (buf0): nothing stages into buf0 afterwards ----
    WAIT_NC();
    __builtin_amdgcn_s_barrier();
    __builtin_amdgcn_sched_barrier(0);
    LOADFRAGS(0);
    LGKM_HALF();
    __builtin_amdgcn_sched_barrier(0);
    MFMAS_KS(0);
    asm volatile("s_waitcnt lgkmcnt(0)" ::: "memory");
    __builtin_amdgcn_sched_barrier(0);
    MFMAS_KS(1);

    // ---- peel window NIT-1 (buf1) ----
    asm volatile("s_waitcnt vmcnt(0)" ::: "memory");
    __builtin_amdgcn_s_barrier();
    __builtin_amdgcn_sched_barrier(0);
    LOADFRAGS(1);
    LGKM_HALF();
    __builtin_amdgcn_sched_barrier(0);
    MFMAS_KS(0);
    asm volatile("s_waitcnt lgkmcnt(0)" ::: "memory");
    __builtin_amdgcn_sched_barrier(0);
    MFMAS_KS(1);

    if constexpr (SPLIT) {
        // ---- pair combine through LDS (reuse staging space; 16KB total) ----
        __syncthreads();
        if (pair == 1) {
#pragma unroll
            for (int mi = 0; mi < 4; ++mi)
#pragma unroll
                for (int ni = 0; ni < 2; ++ni)
                    *(i32x4*)&smem[nh * 8192 + (mi * 2 + ni) * 1024 + lane * 16] = acc[mi][ni];
        }
        __syncthreads();
        if (pair == 1) return;
#pragma unroll
        for (int mi = 0; mi < 4; ++mi)
#pragma unroll
            for (int ni = 0; ni < 2; ++ni) {
                const i32x4 other = *(const i32x4*)&smem[nh * 8192 + (mi * 2 + ni) * 1024 + lane * 16];
                acc[mi][ni] = acc[mi][ni] * 128 + other;   // 128*hi + lo
            }
    }

    // ---- epilogue: dequant, add quantized bias, act fake-quant ----
    float alpha = (*wmax) * (1.0f / 127.0f);
    if (FINAL) alpha *= *s_pre;      // conv2: acc * (s_a1 * s_w2)
    if (SPLIT) alpha *= XQ_DELTA;    // conv1: fixed-point dequant
    const float sact = *s_act;

    float bv[2];
#pragma unroll
    for (int ni = 0; ni < 2; ++ni)
        bv[ni] = bias[n0 + nfix + ni * 16 + l16];

#pragma unroll
    for (int mi = 0; mi < MA; ++mi) {
#pragma unroll
        for (int i = 0; i < 4; ++i) {
            const int m = m0 + mrow0 + mi * 16 + quad * 4 + i;   // D row = quad*4+i
            const int b = m / HW;
            const int rem = m - b * HW;
            const int oh = rem / HOUT;
            const int ow = rem - oh * HOUT;
#pragma unroll
            for (int ni = 0; ni < 2; ++ni) {
                const int col = n0 + nfix + ni * 16 + l16;   // D col = l16
                const float v = (float)acc[mi][ni][i] * alpha + bv[ni];
                float q = rintf(v / sact);
                q = fminf(fmaxf(q, -128.0f), 127.0f);
                if (FINAL) {
                    out_final[(b * 512 + col) * HW + oh * HOUT + ow] = q * sact;
                } else {
                    act_out[(b * 256 + (oh + 1) * 16 + (ow + 1)) * 512 + col] = (signed char)(int)q;
                }
            }
        }
    }
}

// ---------------- launch ----------------
extern "C" void kernel_launch(void* const* d_in, const int* in_sizes, int n_in,
                              void* d_out, int out_size, void* d_ws, size_t ws_size,
                              hipStream_t stream) {
    const float* x  = (const float*)d_in[0];   // 64x256x28x28
    const float* w1 = (const float*)d_in[1];   // 512x256x3x3
    const float* b1 = (const float*)d_in[2];   // 512
    const float* w2 = (const float*)d_in[3];   // 512x512x3x3
    const float* b2 = (const float*)d_in[4];   // 512
    const float* in_scale   = (const float*)d_in[5];
    const float* act1_scale = (const float*)d_in[6];
    const float* act2_scale = (const float*)d_in[7];
    float* out = (float*)d_out;                // 64x512x14x14 NCHW fp32

    char* ws = (char*)d_ws;
    float* part = (float*)(ws + 0);                     // 512 floats
    float* wmax = (float*)(ws + 2048);                  // 2 floats
    float* bq1 = (float*)(ws + 2176);                   // 512 f
    float* bq2 = (float*)(ws + 4224);                   // 512 f
    signed char* wq1 = (signed char*)(ws + 8192);       // 512*2304 = 1,179,648
    signed char* wq2 = (signed char*)(ws + 1187840);    // 512*4608 = 2,359,296
    signed char* xhi = (signed char*)(ws + 3547136);    // 64*900*256 = 14,745,600
    signed char* xlo = (signed char*)(ws + 18292736);   // 14,745,600
    signed char* act = (signed char*)(ws + 33038336);   // 64*256*512 = 8,388,608 -> ends 41,426,944

    // dispatch 1: absmax partials + halos + x transform (independent work fused)
    fused_pre_kernel<<<3120, 256, 0, stream>>>(x, w1, w2, part, xhi, xlo, act);

    // dispatch 2: weight quant+transpose + bias quant + wmax (depends on partials)
    prep_w_kernel<<<1025, 256, 0, stream>>>(w1, w2, b1, b2, part, in_scale, act1_scale,
                                            wq1, wq2, bq1, bq2, wmax);

    // conv1: 256->512, s2, padded 30x30 in, hi/lo limb pairs, padded act codes out
    conv_gemm_kernel<256, 2, 30, 14, true, false><<<dim3(8, 196), 256, 0, stream>>>(
        xhi, xlo, wq1, bq1, wmax, act1_scale, act1_scale, act, nullptr);

    // conv2: 512->512, s1, padded 16x16 in (exact i8 codes), full-K per wave, fp32 NCHW out
    conv_gemm_kernel<512, 1, 16, 14, false, true><<<dim3(8, 196), 256, 0, stream>>>(
        act, nullptr, wq2, bq2, wmax + 1, act1_scale, act2_scale, nullptr, out);
}